// Round 9
// baseline (165.403 us; speedup 1.0000x reference)
//
#include <hip/hip_runtime.h>

#define AREA 4096

typedef short short8 __attribute__((ext_vector_type(8)));
typedef float f32x4 __attribute__((ext_vector_type(4)));

__device__ __forceinline__ unsigned bf16_rn(float x) {
    unsigned u = __builtin_bit_cast(unsigned, x);
    u += 0x7fffu + ((u >> 16) & 1u);
    return u >> 16;
}
__device__ __forceinline__ float bflo(unsigned u) { return __builtin_bit_cast(float, u << 16); }
__device__ __forceinline__ float bfhi(unsigned u) { return __builtin_bit_cast(float, u & 0xffff0000u); }
__device__ __forceinline__ float gelu_f(float x) {
    return 0.5f * x * (1.f + erff(x * 0.70710678118654752f));
}

// ---- stage 32 rows of W (f32 [o][CIN]) into lds_a as bf16-pair words ----
// lds_a[o*AW + cu] ; AW = CIN/2 + 4 (16B-aligned frag reads)
template<int CIN>
__device__ __forceinline__ void stage_A(const float* __restrict__ Wrow0,
                                        unsigned* lds_a, int tid) {
    const int AW = CIN / 2 + 4;
    for (int i = tid; i < 32 * CIN / 4; i += 256) {
        int o = i / (CIN / 4);
        int c4 = i - o * (CIN / 4);
        float4 f = *(const float4*)(Wrow0 + (long)o * CIN + c4 * 4);
        lds_a[o * AW + c4 * 2]     = bf16_rn(f.x) | (bf16_rn(f.y) << 16);
        lds_a[o * AW + c4 * 2 + 1] = bf16_rn(f.z) | (bf16_rn(f.w) << 16);
    }
}

// ---- stage 32ch x 256px f32 chan-major tile into lds_b frag-order -------
// lds_b[px*20 + cpair] = bf16(X[c0+2cp][px]) | bf16(X[c0+2cp+1][px])<<16
__device__ __forceinline__ void stage_B(const float* __restrict__ Xbase,
                                        unsigned* lds_b, int tid) {
#pragma unroll
    for (int j = 0; j < 4; ++j) {
        int cpair = j * 4 + (tid >> 6);
        int px0 = (tid & 63) * 4;
        const float* r0 = Xbase + (long)(2 * cpair) * AREA + px0;
        float4 a = *(const float4*)r0;
        float4 b = *(const float4*)(r0 + AREA);
        lds_b[(px0 + 0) * 20 + cpair] = bf16_rn(a.x) | (bf16_rn(b.x) << 16);
        lds_b[(px0 + 1) * 20 + cpair] = bf16_rn(a.y) | (bf16_rn(b.y) << 16);
        lds_b[(px0 + 2) * 20 + cpair] = bf16_rn(a.z) | (bf16_rn(b.z) << 16);
        lds_b[(px0 + 3) * 20 + cpair] = bf16_rn(a.w) | (bf16_rn(b.w) << 16);
    }
}

// ---- fused q/k/v projection: f32 chan-major in, LDS transpose, MFMA -----
// z 0..1: q -> qp_u (bf16 site-major); z 2..5: k -> kv[..,0:12];
// z 6..9: v -> kv[..,12:24]
__global__ __launch_bounds__(256) void proj_qkv2(
    const float* __restrict__ q, const float* __restrict__ k,
    const float* __restrict__ v,
    const float* __restrict__ Wq, const float* __restrict__ Wk,
    const float* __restrict__ Wv,
    const float* __restrict__ bq, const float* __restrict__ bk,
    const float* __restrict__ bv,
    unsigned* __restrict__ qp_u, unsigned* __restrict__ kv_u)
{
    __shared__ unsigned lds_a[32 * 148];
    __shared__ unsigned lds_b[256 * 20];
    const int z = blockIdx.z;
    const float* Xf; const float* W; const float* bias;
    int outmode, voff, n;
    if (z < 2)      { Xf = q; W = Wq; bias = bq; outmode = 1; voff = 0;  n = z; }
    else if (z < 6) { Xf = k; W = Wk; bias = bk; outmode = 2; voff = 0;  n = z - 2; }
    else            { Xf = v; W = Wv; bias = bv; outmode = 2; voff = 12; n = z - 6; }

    const int tid = threadIdx.x;
    const int lane = tid & 63;
    const int w = tid >> 6;
    const int ot0 = blockIdx.y * 2;
    const int pwb = blockIdx.x * 256;
    const int lcol = lane & 15;
    const int lrow = lane >> 4;
    const int AW = 148;

    stage_A<288>(W + (long)blockIdx.y * 32 * 288, lds_a, tid);

    f32x4 acc[2][4];
#pragma unroll
    for (int m = 0; m < 2; ++m)
#pragma unroll
        for (int s = 0; s < 4; ++s) acc[m][s] = (f32x4){0.f, 0.f, 0.f, 0.f};

    const float* Xn = Xf + (long)n * 288 * AREA + pwb;
    for (int ks = 0; ks < 9; ++ks) {
        __syncthreads();
        stage_B(Xn + (long)(ks * 32) * AREA, lds_b, tid);
        __syncthreads();
        uint4 a0 = *(const uint4*)&lds_a[(0 * 16 + lcol) * AW + ks * 16 + lrow * 4];
        uint4 a1 = *(const uint4*)&lds_a[(1 * 16 + lcol) * AW + ks * 16 + lrow * 4];
        short8 A0 = __builtin_bit_cast(short8, a0);
        short8 A1 = __builtin_bit_cast(short8, a1);
#pragma unroll
        for (int s = 0; s < 4; ++s) {
            uint4 bb = *(const uint4*)&lds_b[(w * 64 + s * 16 + lcol) * 20 + lrow * 4];
            short8 B = __builtin_bit_cast(short8, bb);
            acc[0][s] = __builtin_amdgcn_mfma_f32_16x16x32_bf16(A0, B, acc[0][s], 0, 0, 0);
            acc[1][s] = __builtin_amdgcn_mfma_f32_16x16x32_bf16(A1, B, acc[1][s], 0, 0, 0);
        }
    }

#pragma unroll
    for (int m = 0; m < 2; ++m) {
        const int obase = (ot0 + m) * 16 + lrow * 4;
        const float b0 = bias[obase], b1 = bias[obase + 1];
        const float b2 = bias[obase + 2], b3 = bias[obase + 3];
#pragma unroll
        for (int s = 0; s < 4; ++s) {
            const int pcol = pwb + w * 64 + s * 16 + lcol;
            f32x4 a = acc[m][s];
            float v0 = a[0] + b0, v1 = a[1] + b1, v2 = a[2] + b2, v3 = a[3] + b3;
            uint2 st;
            st.x = bf16_rn(v0) | (bf16_rn(v1) << 16);
            st.y = bf16_rn(v2) | (bf16_rn(v3) << 16);
            if (outmode == 1) {
                *(uint2*)(qp_u + ((long)n * AREA + pcol) * 144 + (obase >> 1)) = st;
            } else {
                int g = obase / 24, d0 = obase % 24;
                *(uint2*)(kv_u + ((long)(n * 12 + g) * AREA + pcol) * 24 + voff + (d0 >> 1)) = st;
            }
        }
    }
}

// ---- FFN projection: bf16 site-major B (direct global), A from f32 W ----
// OUT 0: f32 chan-major + residual (FFN2)   OUT 3: bf16 site-major + GELU
template<int OUT, int CIN>
__global__ __launch_bounds__(256) void proj_ffn(
    const unsigned* __restrict__ Xu, const float* __restrict__ W,
    const float* __restrict__ bias, void* __restrict__ outp,
    const float* __restrict__ res, int RSu)
{
    const int AW = CIN / 2 + 4;
    __shared__ unsigned lds_a[32 * (CIN / 2 + 4)];
    const int tid = threadIdx.x;
    const int lane = tid & 63;
    const int w = tid >> 6;
    const int n = blockIdx.z;
    const int ot0 = blockIdx.y * 2;
    const int pw = blockIdx.x * 256 + w * 64;
    const int lcol = lane & 15;
    const int lrow = lane >> 4;

    stage_A<CIN>(W + (long)blockIdx.y * 32 * CIN, lds_a, tid);
    __syncthreads();

    const uint4* xrow[4];
#pragma unroll
    for (int s = 0; s < 4; ++s)
        xrow[s] = (const uint4*)(Xu + ((long)n * AREA + pw + s * 16 + lcol) * RSu);

    f32x4 acc[2][4];
#pragma unroll
    for (int m = 0; m < 2; ++m)
#pragma unroll
        for (int s = 0; s < 4; ++s) acc[m][s] = (f32x4){0.f, 0.f, 0.f, 0.f};

    for (int ks = 0; ks < CIN / 32; ++ks) {
        uint4 a0 = *(const uint4*)&lds_a[(0 * 16 + lcol) * AW + ks * 16 + lrow * 4];
        uint4 a1 = *(const uint4*)&lds_a[(1 * 16 + lcol) * AW + ks * 16 + lrow * 4];
        short8 A0 = __builtin_bit_cast(short8, a0);
        short8 A1 = __builtin_bit_cast(short8, a1);
#pragma unroll
        for (int s = 0; s < 4; ++s) {
            short8 B = __builtin_bit_cast(short8, xrow[s][ks * 4 + lrow]);
            acc[0][s] = __builtin_amdgcn_mfma_f32_16x16x32_bf16(A0, B, acc[0][s], 0, 0, 0);
            acc[1][s] = __builtin_amdgcn_mfma_f32_16x16x32_bf16(A1, B, acc[1][s], 0, 0, 0);
        }
    }

#pragma unroll
    for (int m = 0; m < 2; ++m) {
        const int obase = (ot0 + m) * 16 + lrow * 4;
        const float b0 = bias[obase], b1 = bias[obase + 1];
        const float b2 = bias[obase + 2], b3 = bias[obase + 3];
#pragma unroll
        for (int s = 0; s < 4; ++s) {
            const int pcol = pw + s * 16 + lcol;
            f32x4 a = acc[m][s];
            float v0 = a[0] + b0, v1 = a[1] + b1, v2 = a[2] + b2, v3 = a[3] + b3;
            if (OUT == 3) {
                v0 = gelu_f(v0); v1 = gelu_f(v1); v2 = gelu_f(v2); v3 = gelu_f(v3);
                uint2 st;
                st.x = bf16_rn(v0) | (bf16_rn(v1) << 16);
                st.y = bf16_rn(v2) | (bf16_rn(v3) << 16);
                *(uint2*)((unsigned*)outp + ((long)n * AREA + pcol) * 288 + (obase >> 1)) = st;
            } else {
                float* fb = (float*)outp;
                float vals[4] = {v0, v1, v2, v3};
#pragma unroll
                for (int r = 0; r < 4; ++r) {
                    long addr = ((long)n * 288 + obase + r) * AREA + pcol;
                    fb[addr] = vals[r] + res[addr];
                }
            }
        }
    }
}

// ---------------- deformable attention ---------------------------------
// 4 lanes/site: bit0 = role (K/V), bit1 = clip partition; XCD swizzle.
__global__ __launch_bounds__(256) void deform_attn_kernel(
    const unsigned* __restrict__ qp, const unsigned* __restrict__ kv,
    const float* __restrict__ offs, float* __restrict__ o,
    unsigned* __restrict__ ot)
{
    const int bid = blockIdx.x;
    const int swz = (bid & 7) * 192 + (bid >> 3);    // 1536 = 8 * 192, bijective
    const int t = swz * 256 + threadIdx.x;
    const int role = t & 1;
    const int clip = (t >> 1) & 1;
    const int site = t >> 2;                 // (b*12 + g)*A + a
    const int a = site & (AREA - 1);
    const int g = (site >> 12) % 12;
    const int b = site / (12 * AREA);
    const int py = a >> 6, px = a & 63;
    const float scale = 0.20412414523193150818f;   // 1/sqrt(24)

    float qv[24];
    {
        const uint4* qb = (const uint4*)(qp + ((long)b * AREA + a) * 144 + g * 12);
        uint4 q0 = qb[0], q1 = qb[1], q2 = qb[2];
        unsigned uq[12] = {q0.x, q0.y, q0.z, q0.w, q1.x, q1.y, q1.z, q1.w,
                           q2.x, q2.y, q2.z, q2.w};
#pragma unroll
        for (int j = 0; j < 12; ++j) {
            qv[2 * j]     = bflo(uq[j]) * scale;
            qv[2 * j + 1] = bfhi(uq[j]) * scale;
        }
    }

    float m = -1e30f, l = 0.f;
    float outv[24];
#pragma unroll
    for (int d = 0; d < 24; ++d) outv[d] = 0.f;

    const unsigned* __restrict__ cb =
        kv + (long)((b * 2 + clip) * 12 + g) * AREA * 24 + role * 12;
    const float* __restrict__ obase =
        offs + ((long)b * 432 + (clip * 12 + g) * 18) * AREA;
#pragma unroll 3
    for (int k = 0; k < 9; ++k) {
        float oy = obase[(long)(2 * k) * AREA + a];
        float ox = obase[(long)(2 * k + 1) * AREA + a];
        int ky = k / 3, kx = k - ky * 3;
        float ys = (float)(py + ky - 1) + oy;
        float xs_ = (float)(px + kx - 1) + ox;
        float y0f = floorf(ys), x0f = floorf(xs_);
        float dy = ys - y0f, dx = xs_ - x0f;
        float wy[2] = {1.f - dy, dy};
        float wx[2] = {1.f - dx, dx};
        long  idx4[4];
        float w4[4];
#pragma unroll
        for (int cy = 0; cy < 2; ++cy) {
            float yc = y0f + (float)cy;
            bool vy = (yc >= 0.f) && (yc <= 63.f);
            int yi = (int)fminf(fmaxf(yc, 0.f), 63.f);
#pragma unroll
            for (int cx = 0; cx < 2; ++cx) {
                float xc = x0f + (float)cx;
                bool vx = (xc >= 0.f) && (xc <= 63.f);
                int xi = (int)fminf(fmaxf(xc, 0.f), 63.f);
                w4[cy * 2 + cx] = wy[cy] * wx[cx] * ((vy && vx) ? 1.f : 0.f);
                idx4[cy * 2 + cx] = (long)(yi * 64 + xi) * 24;
            }
        }
        float xs[24];
#pragma unroll
        for (int j = 0; j < 24; ++j) xs[j] = 0.f;
        float sh = 0.f;
#pragma unroll
        for (int c = 0; c < 4; ++c) {
            const uint4* pc = (const uint4*)(cb + idx4[c]);
            uint4 u0 = pc[0], u1 = pc[1], u2 = pc[2];
            unsigned uu[12] = {u0.x, u0.y, u0.z, u0.w,
                               u1.x, u1.y, u1.z, u1.w,
                               u2.x, u2.y, u2.z, u2.w};
            float w = w4[c];
            float d = 0.f;
#pragma unroll
            for (int j = 0; j < 12; ++j) {
                float lo = bflo(uu[j]), hi = bfhi(uu[j]);
                d = fmaf(qv[2 * j], lo, d);
                d = fmaf(qv[2 * j + 1], hi, d);
                xs[2 * j]     = fmaf(w, lo, xs[2 * j]);
                xs[2 * j + 1] = fmaf(w, hi, xs[2 * j + 1]);
            }
            sh = fmaf(w, d, sh);
        }
        float sx = __shfl_xor(sh, 1);
        float s = role ? sx : sh;          // K-lane's full dot
        float mn = fmaxf(m, s);
        float corr = __expf(m - mn);
        float p = __expf(s - mn);
        l = l * corr + p;
        m = mn;
#pragma unroll
        for (int j = 0; j < 24; ++j)
            outv[j] = fmaf(outv[j], corr, p * xs[j]);
    }

    // ---- merge the two clip partitions (lanes differing in bit 1) ----
    float mo  = __shfl_xor(m, 2);
    float lo2 = __shfl_xor(l, 2);
    float mn = fmaxf(m, mo);
    float fs = __expf(m - mn), fo = __expf(mo - mn);
    float lm = l * fs + lo2 * fo;
    float inv = 1.f / lm;
#pragma unroll
    for (int d = 0; d < 24; ++d) {
        float ovo = __shfl_xor(outv[d], 2);
        outv[d] = (outv[d] * fs + ovo * fo) * inv;
    }

    if (role == 1 && clip == 0) {
        float ov[24];
#pragma unroll
        for (int d = 0; d < 24; ++d) {
            ov[d] = outv[d];
            o[((long)b * 288 + g * 24 + d) * AREA + a] = ov[d];
        }
        unsigned* tb = ot + ((long)b * AREA + a) * 144 + g * 12;
        uint4 s0, s1, s2;
        s0.x = bf16_rn(ov[0])  | (bf16_rn(ov[1])  << 16);
        s0.y = bf16_rn(ov[2])  | (bf16_rn(ov[3])  << 16);
        s0.z = bf16_rn(ov[4])  | (bf16_rn(ov[5])  << 16);
        s0.w = bf16_rn(ov[6])  | (bf16_rn(ov[7])  << 16);
        s1.x = bf16_rn(ov[8])  | (bf16_rn(ov[9])  << 16);
        s1.y = bf16_rn(ov[10]) | (bf16_rn(ov[11]) << 16);
        s1.z = bf16_rn(ov[12]) | (bf16_rn(ov[13]) << 16);
        s1.w = bf16_rn(ov[14]) | (bf16_rn(ov[15]) << 16);
        s2.x = bf16_rn(ov[16]) | (bf16_rn(ov[17]) << 16);
        s2.y = bf16_rn(ov[18]) | (bf16_rn(ov[19]) << 16);
        s2.z = bf16_rn(ov[20]) | (bf16_rn(ov[21]) << 16);
        s2.w = bf16_rn(ov[22]) | (bf16_rn(ov[23]) << 16);
        ((uint4*)tb)[0] = s0; ((uint4*)tb)[1] = s1; ((uint4*)tb)[2] = s2;
    }
}

extern "C" void kernel_launch(void* const* d_in, const int* in_sizes, int n_in,
                              void* d_out, int out_size, void* d_ws, size_t ws_size,
                              hipStream_t stream) {
    const float* q      = (const float*)d_in[0];
    const float* k      = (const float*)d_in[1];
    const float* v      = (const float*)d_in[2];
    const float* offset = (const float*)d_in[3];
    const float* Wq     = (const float*)d_in[4];
    const float* bq     = (const float*)d_in[5];
    const float* Wk     = (const float*)d_in[6];
    const float* bk     = (const float*)d_in[7];
    const float* Wv     = (const float*)d_in[8];
    const float* bv     = (const float*)d_in[9];
    const float* W1     = (const float*)d_in[10];
    const float* b1     = (const float*)d_in[11];
    const float* W2     = (const float*)d_in[12];
    const float* b2     = (const float*)d_in[13];
    float* out = (float*)d_out;
    float* ws  = (float*)d_ws;

    unsigned* qp_u = (unsigned*)ws;                    // 1,179,648 u32
    unsigned* kv_u = (unsigned*)(ws + 2359296);        // 4,718,592 u32
    unsigned* o_t  = (unsigned*)(ws + 8257536);        // 1,179,648 u32
    unsigned* x1   = (unsigned*)(ws + 10616832);       // 2,359,296 u32

    // 1) fused q/k/v projections (in-kernel transpose + W pack)
    proj_qkv2<<<dim3(16, 9, 10), dim3(256), 0, stream>>>(
        q, k, v, Wq, Wk, Wv, bq, bk, bv, qp_u, kv_u);
    // 2) deformable attention -> d_out (f32) + o_t (bf16 site-major)
    deform_attn_kernel<<<dim3(1536), dim3(256), 0, stream>>>(
        qp_u, kv_u, offset, out, o_t);
    // 3) FFN1: o_t(288) -> x1(576) bf16 site-major, GELU
    proj_ffn<3, 288><<<dim3(16, 18, 2), dim3(256), 0, stream>>>(
        o_t, W1, b1, x1, nullptr, 144);
    // 4) FFN2: x1(576) -> d_out f32 chan-major + residual o
    proj_ffn<0, 576><<<dim3(16, 9, 2), dim3(256), 0, stream>>>(
        x1, W2, b2, out, out, 288);
}

// Round 10
// 149.357 us; speedup vs baseline: 1.1074x; 1.1074x over previous
//
#include <hip/hip_runtime.h>

#define AREA 4096

typedef short short8 __attribute__((ext_vector_type(8)));
typedef float f32x4 __attribute__((ext_vector_type(4)));

__device__ __forceinline__ unsigned bf16_rn(float x) {
    unsigned u = __builtin_bit_cast(unsigned, x);
    u += 0x7fffu + ((u >> 16) & 1u);
    return u >> 16;
}
__device__ __forceinline__ float bflo(unsigned u) { return __builtin_bit_cast(float, u << 16); }
__device__ __forceinline__ float bfhi(unsigned u) { return __builtin_bit_cast(float, u & 0xffff0000u); }
__device__ __forceinline__ float gelu_f(float x) {
    return 0.5f * x * (1.f + erff(x * 0.70710678118654752f));
}

// shared bilinear corner computation (must be identical in both attn phases)
__device__ __forceinline__ void bilin(int k, int py, int px, float oy, float ox,
                                      int* idx4, float* w4) {
    int ky = k / 3, kx = k - ky * 3;
    float ys = (float)(py + ky - 1) + oy;
    float xs = (float)(px + kx - 1) + ox;
    float y0f = floorf(ys), x0f = floorf(xs);
    float dy = ys - y0f, dx = xs - x0f;
    float wy[2] = {1.f - dy, dy}, wx[2] = {1.f - dx, dx};
#pragma unroll
    for (int cy = 0; cy < 2; ++cy) {
        float yc = y0f + (float)cy;
        bool vy = (yc >= 0.f) && (yc <= 63.f);
        int yi = (int)fminf(fmaxf(yc, 0.f), 63.f);
#pragma unroll
        for (int cx = 0; cx < 2; ++cx) {
            float xc = x0f + (float)cx;
            bool vx = (xc >= 0.f) && (xc <= 63.f);
            int xi = (int)fminf(fmaxf(xc, 0.f), 63.f);
            w4[cy * 2 + cx] = wy[cy] * wx[cx] * ((vy && vx) ? 1.f : 0.f);
            idx4[cy * 2 + cx] = yi * 64 + xi;
        }
    }
}

// W-frag tile offsets (in uint4 units)
#define OFF_Q 0
#define OFF_K (162 * 64)
#define OFF_V (324 * 64)
#define OFF_1 (486 * 64)
#define OFF_2 (810 * 64)

// ---- prep: y=0/1/2 transpose q/k/v to pixel-major bf16; y=3 pack weights --
__global__ __launch_bounds__(256) void prep_kernel(
    const float* __restrict__ q, const float* __restrict__ k,
    const float* __restrict__ v,
    const float* __restrict__ Wq, const float* __restrict__ Wk,
    const float* __restrict__ Wv, const float* __restrict__ W1,
    const float* __restrict__ W2,
    unsigned* __restrict__ xq, unsigned* __restrict__ xk,
    unsigned* __restrict__ xv, uint4* __restrict__ wp)
{
    if (blockIdx.y < 3) {
        const float* src; unsigned* dst; int nimg;
        switch (blockIdx.y) {
            case 0: src = q; dst = xq; nimg = 2; break;
            case 1: src = k; dst = xk; nimg = 4; break;
            default:src = v; dst = xv; nimg = 4; break;
        }
        int idx = blockIdx.x * 256 + threadIdx.x;
        if (idx >= nimg * AREA * 36) return;
        int a = idx & (AREA - 1);
        int rest = idx >> 12;
        int oct = rest % 36;
        int n = rest / 36;
        const float* s = src + ((long)n * 288 + oct * 8) * AREA + a;
        uint4 u;
        u.x = bf16_rn(s[0])        | (bf16_rn(s[AREA])     << 16);
        u.y = bf16_rn(s[2 * AREA]) | (bf16_rn(s[3 * AREA]) << 16);
        u.z = bf16_rn(s[4 * AREA]) | (bf16_rn(s[5 * AREA]) << 16);
        u.w = bf16_rn(s[6 * AREA]) | (bf16_rn(s[7 * AREA]) << 16);
        *(uint4*)(dst + ((long)n * AREA + a) * 144 + oct * 4) = u;
    } else {
        int gw = blockIdx.x * 4 + (threadIdx.x >> 6);
        if (gw >= 1134) return;
        int lane = threadIdx.x & 63;
        const float* W; int Cin, KS, local, off;
        if      (gw < 162) { W = Wq; Cin = 288; KS = 9;  local = gw;       off = OFF_Q; }
        else if (gw < 324) { W = Wk; Cin = 288; KS = 9;  local = gw - 162; off = OFF_K; }
        else if (gw < 486) { W = Wv; Cin = 288; KS = 9;  local = gw - 324; off = OFF_V; }
        else if (gw < 810) { W = W1; Cin = 288; KS = 9;  local = gw - 486; off = OFF_1; }
        else               { W = W2; Cin = 576; KS = 18; local = gw - 810; off = OFF_2; }
        int ot = local / KS, ks = local - ot * KS;
        int o = ot * 16 + (lane & 15);
        int c0 = ks * 32 + ((lane >> 4) << 3);
        const float4* wr = (const float4*)(W + (long)o * Cin + c0);
        float4 f0 = wr[0], f1 = wr[1];
        uint4 u;
        u.x = bf16_rn(f0.x) | (bf16_rn(f0.y) << 16);
        u.y = bf16_rn(f0.z) | (bf16_rn(f0.w) << 16);
        u.z = bf16_rn(f1.x) | (bf16_rn(f1.y) << 16);
        u.w = bf16_rn(f1.z) | (bf16_rn(f1.w) << 16);
        wp[(long)off + (long)local * 64 + lane] = u;
    }
}

// ---- fused q/k/v MFMA projection ----------------------------------------
// z 0..1: q -> qp_u (bf16 site-major [b][a][144]);
// z 2..5: k -> k_u [(n*12+g)*2+half][a][6 u32]  (half = ch>=12)
// z 6..9: v -> v_u [n*12+g][a][12 u32]
__global__ __launch_bounds__(256) void proj_qkv(
    const unsigned* __restrict__ xq, const unsigned* __restrict__ xk,
    const unsigned* __restrict__ xv, const uint4* __restrict__ wp,
    const float* __restrict__ bq, const float* __restrict__ bk,
    const float* __restrict__ bv, unsigned* __restrict__ qp_u,
    unsigned* __restrict__ k_u, unsigned* __restrict__ v_u)
{
    const int z = blockIdx.z;
    const unsigned* Xt; const uint4* Wp; const float* bias;
    int outmode, n;
    if (z < 2)      { Xt = xq; Wp = wp + OFF_Q; bias = bq; outmode = 0; n = z; }
    else if (z < 6) { Xt = xk; Wp = wp + OFF_K; bias = bk; outmode = 1; n = z - 2; }
    else            { Xt = xv; Wp = wp + OFF_V; bias = bv; outmode = 2; n = z - 6; }

    const int tid = threadIdx.x;
    const int lane = tid & 63;
    const int w = tid >> 6;
    const int ot0 = blockIdx.y * 2;
    const int pw = blockIdx.x * 256 + w * 64;
    const int lcol = lane & 15;
    const int lrow = lane >> 4;

    const uint4* xrow[4];
#pragma unroll
    for (int s = 0; s < 4; ++s)
        xrow[s] = (const uint4*)(Xt + ((long)n * AREA + pw + s * 16 + lcol) * 144);
    const uint4* wa0 = Wp + (long)ot0 * 9 * 64 + lane;
    const uint4* wa1 = Wp + (long)(ot0 + 1) * 9 * 64 + lane;

    f32x4 acc[2][4];
#pragma unroll
    for (int m = 0; m < 2; ++m)
#pragma unroll
        for (int s = 0; s < 4; ++s) acc[m][s] = (f32x4){0.f, 0.f, 0.f, 0.f};

    for (int ks = 0; ks < 9; ++ks) {
        uint4 a0 = wa0[(long)ks * 64];
        uint4 a1 = wa1[(long)ks * 64];
        uint4 b[4];
#pragma unroll
        for (int s = 0; s < 4; ++s) b[s] = xrow[s][ks * 4 + lrow];
        short8 A0 = __builtin_bit_cast(short8, a0);
        short8 A1 = __builtin_bit_cast(short8, a1);
#pragma unroll
        for (int s = 0; s < 4; ++s) {
            short8 B = __builtin_bit_cast(short8, b[s]);
            acc[0][s] = __builtin_amdgcn_mfma_f32_16x16x32_bf16(A0, B, acc[0][s], 0, 0, 0);
            acc[1][s] = __builtin_amdgcn_mfma_f32_16x16x32_bf16(A1, B, acc[1][s], 0, 0, 0);
        }
    }

#pragma unroll
    for (int m = 0; m < 2; ++m) {
        const int obase = (ot0 + m) * 16 + lrow * 4;
        const float b0 = bias[obase], b1 = bias[obase + 1];
        const float b2 = bias[obase + 2], b3 = bias[obase + 3];
#pragma unroll
        for (int s = 0; s < 4; ++s) {
            const int pcol = pw + s * 16 + lcol;
            f32x4 a = acc[m][s];
            float v0 = a[0] + b0, v1 = a[1] + b1, v2 = a[2] + b2, v3 = a[3] + b3;
            uint2 st;
            st.x = bf16_rn(v0) | (bf16_rn(v1) << 16);
            st.y = bf16_rn(v2) | (bf16_rn(v3) << 16);
            if (outmode == 0) {
                *(uint2*)(qp_u + ((long)n * AREA + pcol) * 144 + (obase >> 1)) = st;
            } else if (outmode == 1) {
                int g = obase / 24, d0 = obase % 24;
                int half = d0 >= 12 ? 1 : 0;
                int slab = n * 12 + g;
                *(uint2*)(k_u + ((long)(slab * 2 + half) * AREA + pcol) * 6
                          + ((d0 % 12) >> 1)) = st;
            } else {
                int g = obase / 24, d0 = obase % 24;
                *(uint2*)(v_u + ((long)(n * 12 + g) * AREA + pcol) * 12 + (d0 >> 1)) = st;
            }
        }
    }
}

// ---- FFN MFMA projection (from R8, unchanged) ---------------------------
template<int OUT>
__global__ __launch_bounds__(256) void proj_mfma(
    const unsigned* __restrict__ Xt, const uint4* __restrict__ Wp,
    const float* __restrict__ bias, void* __restrict__ outp,
    const float* __restrict__ res, int KS, int RSu)
{
    const int tid = threadIdx.x;
    const int lane = tid & 63;
    const int w = tid >> 6;
    const int n = blockIdx.z;
    const int ot0 = blockIdx.y * 2;
    const int pw = blockIdx.x * 256 + w * 64;
    const int lcol = lane & 15;
    const int lrow = lane >> 4;

    const uint4* xrow[4];
#pragma unroll
    for (int s = 0; s < 4; ++s)
        xrow[s] = (const uint4*)(Xt + ((long)n * AREA + pw + s * 16 + lcol) * RSu);
    const uint4* wa0 = Wp + (long)ot0 * KS * 64 + lane;
    const uint4* wa1 = Wp + (long)(ot0 + 1) * KS * 64 + lane;

    f32x4 acc[2][4];
#pragma unroll
    for (int m = 0; m < 2; ++m)
#pragma unroll
        for (int s = 0; s < 4; ++s) acc[m][s] = (f32x4){0.f, 0.f, 0.f, 0.f};

    for (int ks = 0; ks < KS; ++ks) {
        uint4 a0 = wa0[(long)ks * 64];
        uint4 a1 = wa1[(long)ks * 64];
        uint4 b[4];
#pragma unroll
        for (int s = 0; s < 4; ++s) b[s] = xrow[s][ks * 4 + lrow];
        short8 A0 = __builtin_bit_cast(short8, a0);
        short8 A1 = __builtin_bit_cast(short8, a1);
#pragma unroll
        for (int s = 0; s < 4; ++s) {
            short8 B = __builtin_bit_cast(short8, b[s]);
            acc[0][s] = __builtin_amdgcn_mfma_f32_16x16x32_bf16(A0, B, acc[0][s], 0, 0, 0);
            acc[1][s] = __builtin_amdgcn_mfma_f32_16x16x32_bf16(A1, B, acc[1][s], 0, 0, 0);
        }
    }

#pragma unroll
    for (int m = 0; m < 2; ++m) {
        const int obase = (ot0 + m) * 16 + lrow * 4;
        const float b0 = bias[obase], b1 = bias[obase + 1];
        const float b2 = bias[obase + 2], b3 = bias[obase + 3];
#pragma unroll
        for (int s = 0; s < 4; ++s) {
            const int pcol = pw + s * 16 + lcol;
            f32x4 a = acc[m][s];
            float v0 = a[0] + b0, v1 = a[1] + b1, v2 = a[2] + b2, v3 = a[3] + b3;
            if (OUT == 3) {
                v0 = gelu_f(v0); v1 = gelu_f(v1); v2 = gelu_f(v2); v3 = gelu_f(v3);
                uint2 st;
                st.x = bf16_rn(v0) | (bf16_rn(v1) << 16);
                st.y = bf16_rn(v2) | (bf16_rn(v3) << 16);
                *(uint2*)((unsigned*)outp + ((long)n * AREA + pcol) * 288 + (obase >> 1)) = st;
            } else {
                float* fb = (float*)outp;
                float vals[4] = {v0, v1, v2, v3};
#pragma unroll
                for (int r = 0; r < 4; ++r) {
                    long addr = ((long)n * 288 + obase + r) * AREA + pcol;
                    fb[addr] = vals[r] + res[addr];
                }
            }
        }
    }
}

// ---- attn phase A: partial logits via LDS-staged K half-slab ------------
// block = (slab=bc*12+g) x half x chunk; 1024 threads; 96KB LDS.
// lg[(((b*12+g)*2+clip)*2+half)*9*A + k*A + a] = partial 12-ch dot (scaled)
__global__ __launch_bounds__(1024) void attn_logits(
    const unsigned* __restrict__ qp, const unsigned* __restrict__ k_u,
    const float* __restrict__ offs, float* __restrict__ lg)
{
    __shared__ unsigned kl[AREA * 6];
    const int bid = blockIdx.x;                       // 384 = 8*48
    const int lid = (bid & 7) * 48 + (bid >> 3);      // XCD swizzle
    const int chunk = lid & 3;
    const int half = (lid >> 2) & 1;
    const int slab = lid >> 3;                        // bc*12+g
    const int g = slab % 12;
    const int bc = slab / 12;
    const int b = bc >> 1, clip = bc & 1;
    const int tid = threadIdx.x;

    const unsigned* ks = k_u + (long)(slab * 2 + half) * AREA * 6;
#pragma unroll
    for (int i = 0; i < 4; ++i) {
        int px = i * 1024 + tid;
        uint2 a0 = *(const uint2*)(ks + (long)px * 6);
        uint2 a1 = *(const uint2*)(ks + (long)px * 6 + 2);
        uint2 a2 = *(const uint2*)(ks + (long)px * 6 + 4);
        *(uint2*)&kl[px * 6]     = a0;
        *(uint2*)&kl[px * 6 + 2] = a1;
        *(uint2*)&kl[px * 6 + 4] = a2;
    }
    __syncthreads();

    const int a = chunk * 1024 + tid;
    const int py = a >> 6, px = a & 63;
    const float scale = 0.20412414523193150818f;      // 1/sqrt(24)
    float qv[12];
    {
        const unsigned* qb = qp + ((long)b * AREA + a) * 144 + g * 12 + half * 6;
#pragma unroll
        for (int j = 0; j < 6; ++j) {
            unsigned u = qb[j];
            qv[2 * j]     = bflo(u) * scale;
            qv[2 * j + 1] = bfhi(u) * scale;
        }
    }
    const float* ob = offs + ((long)b * 432 + (clip * 12 + g) * 18) * AREA + a;
    float* lout = lg + ((long)(((b * 12 + g) * 2 + clip) * 2 + half) * 9) * AREA + a;

#pragma unroll 3
    for (int k = 0; k < 9; ++k) {
        float oy = ob[(long)(2 * k) * AREA];
        float ox = ob[(long)(2 * k + 1) * AREA];
        int idx4[4]; float w4[4];
        bilin(k, py, px, oy, ox, idx4, w4);
        float s = 0.f;
#pragma unroll
        for (int c = 0; c < 4; ++c) {
            const unsigned* kc = &kl[idx4[c] * 6];
            uint2 u0 = *(const uint2*)kc;
            uint2 u1 = *(const uint2*)(kc + 2);
            uint2 u2 = *(const uint2*)(kc + 4);
            float d = qv[0] * bflo(u0.x) + qv[1] * bfhi(u0.x)
                    + qv[2] * bflo(u0.y) + qv[3] * bfhi(u0.y)
                    + qv[4] * bflo(u1.x) + qv[5] * bfhi(u1.x)
                    + qv[6] * bflo(u1.y) + qv[7] * bfhi(u1.y)
                    + qv[8] * bflo(u2.x) + qv[9] * bfhi(u2.x)
                    + qv[10] * bflo(u2.y) + qv[11] * bfhi(u2.y);
            s = fmaf(w4[c], d, s);
        }
        lout[(long)k * AREA] = s;
    }
}

// ---- attn phase B: softmax (from partial logits) + V weighted sum -------
// 2 lanes/site (clip pair).  V gathered from global.
__global__ __launch_bounds__(256) void attn_vsum(
    const unsigned* __restrict__ v_u, const float* __restrict__ lg,
    const float* __restrict__ offs, float* __restrict__ o,
    unsigned* __restrict__ ot)
{
    const int bid = blockIdx.x;                       // 768 = 8*96
    const int swz = (bid & 7) * 96 + (bid >> 3);
    const int t = swz * 256 + threadIdx.x;
    const int clip = t & 1;
    const int site = t >> 1;
    const int a = site & (AREA - 1);
    const int g = (site >> 12) % 12;
    const int b = site / (12 * AREA);
    const int py = a >> 6, px = a & 63;

    const float* lbase = lg + ((long)(((b * 12 + g) * 2 + clip) * 2) * 9) * AREA + a;
    float s9[9];
    float m9 = -1e30f;
#pragma unroll
    for (int k = 0; k < 9; ++k) {
        s9[k] = lbase[(long)k * AREA] + lbase[(long)(9 + k) * AREA];
        m9 = fmaxf(m9, s9[k]);
    }
    float l9 = 0.f;
#pragma unroll
    for (int k = 0; k < 9; ++k) { s9[k] = __expf(s9[k] - m9); l9 += s9[k]; }
    float mo = __shfl_xor(m9, 1);
    float lo = __shfl_xor(l9, 1);
    float M = fmaxf(m9, mo);
    float fs = __expf(m9 - M);
    float l = l9 * fs + lo * __expf(mo - M);
    float winv = fs / l;          // w_k = s9[k] * winv

    float outv[24];
#pragma unroll
    for (int d = 0; d < 24; ++d) outv[d] = 0.f;

    const unsigned* vb = v_u + (long)((b * 2 + clip) * 12 + g) * AREA * 12;
    const float* ob = offs + ((long)b * 432 + (clip * 12 + g) * 18) * AREA + a;
#pragma unroll 3
    for (int k = 0; k < 9; ++k) {
        float oy = ob[(long)(2 * k) * AREA];
        float ox = ob[(long)(2 * k + 1) * AREA];
        int idx4[4]; float w4[4];
        bilin(k, py, px, oy, ox, idx4, w4);
        float wk = s9[k] * winv;
#pragma unroll
        for (int c = 0; c < 4; ++c) {
            const uint4* pc = (const uint4*)(vb + (long)idx4[c] * 12);
            uint4 u0 = pc[0], u1 = pc[1], u2 = pc[2];
            unsigned uu[12] = {u0.x, u0.y, u0.z, u0.w,
                               u1.x, u1.y, u1.z, u1.w,
                               u2.x, u2.y, u2.z, u2.w};
            float wc = wk * w4[c];
#pragma unroll
            for (int j = 0; j < 12; ++j) {
                outv[2 * j]     = fmaf(wc, bflo(uu[j]), outv[2 * j]);
                outv[2 * j + 1] = fmaf(wc, bfhi(uu[j]), outv[2 * j + 1]);
            }
        }
    }
#pragma unroll
    for (int d = 0; d < 24; ++d) outv[d] += __shfl_xor(outv[d], 1);

    if (clip == 0) {
#pragma unroll
        for (int d = 0; d < 24; ++d)
            o[((long)b * 288 + g * 24 + d) * AREA + a] = outv[d];
        unsigned* tb = ot + ((long)b * AREA + a) * 144 + g * 12;
        uint4 s0, s1, s2;
        s0.x = bf16_rn(outv[0])  | (bf16_rn(outv[1])  << 16);
        s0.y = bf16_rn(outv[2])  | (bf16_rn(outv[3])  << 16);
        s0.z = bf16_rn(outv[4])  | (bf16_rn(outv[5])  << 16);
        s0.w = bf16_rn(outv[6])  | (bf16_rn(outv[7])  << 16);
        s1.x = bf16_rn(outv[8])  | (bf16_rn(outv[9])  << 16);
        s1.y = bf16_rn(outv[10]) | (bf16_rn(outv[11]) << 16);
        s1.z = bf16_rn(outv[12]) | (bf16_rn(outv[13]) << 16);
        s1.w = bf16_rn(outv[14]) | (bf16_rn(outv[15]) << 16);
        s2.x = bf16_rn(outv[16]) | (bf16_rn(outv[17]) << 16);
        s2.y = bf16_rn(outv[18]) | (bf16_rn(outv[19]) << 16);
        s2.z = bf16_rn(outv[20]) | (bf16_rn(outv[21]) << 16);
        s2.w = bf16_rn(outv[22]) | (bf16_rn(outv[23]) << 16);
        ((uint4*)tb)[0] = s0; ((uint4*)tb)[1] = s1; ((uint4*)tb)[2] = s2;
    }
}

extern "C" void kernel_launch(void* const* d_in, const int* in_sizes, int n_in,
                              void* d_out, int out_size, void* d_ws, size_t ws_size,
                              hipStream_t stream) {
    const float* q      = (const float*)d_in[0];
    const float* k      = (const float*)d_in[1];
    const float* v      = (const float*)d_in[2];
    const float* offset = (const float*)d_in[3];
    const float* Wq     = (const float*)d_in[4];
    const float* bq     = (const float*)d_in[5];
    const float* Wk     = (const float*)d_in[6];
    const float* bk     = (const float*)d_in[7];
    const float* Wv     = (const float*)d_in[8];
    const float* bv     = (const float*)d_in[9];
    const float* W1     = (const float*)d_in[10];
    const float* b1     = (const float*)d_in[11];
    const float* W2     = (const float*)d_in[12];
    const float* b2     = (const float*)d_in[13];
    float* out = (float*)d_out;
    float* ws  = (float*)d_ws;

    // ws layout (u32 units); peak 13,266,432 u32 = 53.1 MB (same as R8)
    unsigned* qp_u = (unsigned*)ws;                    //  0        (1,179,648)
    unsigned* k_u  = (unsigned*)(ws + 1179648);        //           (2,359,296)
    unsigned* v_u  = (unsigned*)(ws + 3538944);        //           (2,359,296)
    unsigned* xq   = (unsigned*)(ws + 5898240);        //           (1,179,648)
    unsigned* xk   = (unsigned*)(ws + 7077888);        //           (2,359,296)
    unsigned* xv   = (unsigned*)(ws + 9437184);        //           (2,359,296)
    uint4*    wp   = (uint4*)(ws + 11796480);          //           (290,304)
    unsigned* o_t  = (unsigned*)(ws + 12086784);       //           (1,179,648)
    float*    lg   = (float*)(ws + 5898240);           // alias xq+xk (3,538,944)
    unsigned* x1   = xv;                               // alias xv   (2,359,296)

    // 1) transpose inputs + pack weights
    prep_kernel<<<dim3(2304, 4), dim3(256), 0, stream>>>(
        q, k, v, Wq, Wk, Wv, W1, W2, xq, xk, xv, wp);
    // 2) fused q/k/v projections
    proj_qkv<<<dim3(16, 9, 10), dim3(256), 0, stream>>>(
        xq, xk, xv, wp, bq, bk, bv, qp_u, k_u, v_u);
    // 3a) attn phase A: partial logits (LDS-staged K)
    attn_logits<<<dim3(384), dim3(1024), 0, stream>>>(qp_u, k_u, offset, lg);
    // 3b) attn phase B: softmax + V sum -> d_out (f32) + o_t (bf16 site-major)
    attn_vsum<<<dim3(768), dim3(256), 0, stream>>>(v_u, lg, offset, out, o_t);
    // 4) FFN1: o_t(288) -> x1(576) bf16 site-major, GELU
    proj_mfma<3><<<dim3(16, 18, 2), dim3(256), 0, stream>>>(
        o_t, wp + OFF_1, b1, x1, nullptr, 9, 144);
    // 5) FFN2: x1(576) -> d_out f32 chan-major + residual o
    proj_mfma<0><<<dim3(16, 9, 2), dim3(256), 0, stream>>>(
        x1, wp + OFF_2, b2, out, out, 18, 288);
}

// Round 11
// 147.031 us; speedup vs baseline: 1.1250x; 1.0158x over previous
//
#include <hip/hip_runtime.h>

#define AREA 4096

typedef short short8 __attribute__((ext_vector_type(8)));
typedef float f32x4 __attribute__((ext_vector_type(4)));

__device__ __forceinline__ unsigned bf16_rn(float x) {
    unsigned u = __builtin_bit_cast(unsigned, x);
    u += 0x7fffu + ((u >> 16) & 1u);
    return u >> 16;
}
__device__ __forceinline__ float bflo(unsigned u) { return __builtin_bit_cast(float, u << 16); }
__device__ __forceinline__ float bfhi(unsigned u) { return __builtin_bit_cast(float, u & 0xffff0000u); }
__device__ __forceinline__ float gelu_f(float x) {
    return 0.5f * x * (1.f + erff(x * 0.70710678118654752f));
}

// shared bilinear corner computation (identical in both attn phases)
__device__ __forceinline__ void bilin(int k, int py, int px, float oy, float ox,
                                      int* idx4, float* w4) {
    int ky = k / 3, kx = k - ky * 3;
    float ys = (float)(py + ky - 1) + oy;
    float xs = (float)(px + kx - 1) + ox;
    float y0f = floorf(ys), x0f = floorf(xs);
    float dy = ys - y0f, dx = xs - x0f;
    float wy[2] = {1.f - dy, dy}, wx[2] = {1.f - dx, dx};
#pragma unroll
    for (int cy = 0; cy < 2; ++cy) {
        float yc = y0f + (float)cy;
        bool vy = (yc >= 0.f) && (yc <= 63.f);
        int yi = (int)fminf(fmaxf(yc, 0.f), 63.f);
#pragma unroll
        for (int cx = 0; cx < 2; ++cx) {
            float xc = x0f + (float)cx;
            bool vx = (xc >= 0.f) && (xc <= 63.f);
            int xi = (int)fminf(fmaxf(xc, 0.f), 63.f);
            w4[cy * 2 + cx] = wy[cy] * wx[cx] * ((vy && vx) ? 1.f : 0.f);
            idx4[cy * 2 + cx] = yi * 64 + xi;
        }
    }
}

// W-frag tile offsets (in uint4 units)
#define OFF_Q 0
#define OFF_K (162 * 64)
#define OFF_V (324 * 64)
#define OFF_1 (486 * 64)
#define OFF_2 (810 * 64)

// ---- prep: y=0/1/2 transpose q/k/v to pixel-major bf16; y=3 pack weights --
__global__ __launch_bounds__(256) void prep_kernel(
    const float* __restrict__ q, const float* __restrict__ k,
    const float* __restrict__ v,
    const float* __restrict__ Wq, const float* __restrict__ Wk,
    const float* __restrict__ Wv, const float* __restrict__ W1,
    const float* __restrict__ W2,
    unsigned* __restrict__ xq, unsigned* __restrict__ xk,
    unsigned* __restrict__ xv, uint4* __restrict__ wp)
{
    if (blockIdx.y < 3) {
        const float* src; unsigned* dst; int nimg;
        switch (blockIdx.y) {
            case 0: src = q; dst = xq; nimg = 2; break;
            case 1: src = k; dst = xk; nimg = 4; break;
            default:src = v; dst = xv; nimg = 4; break;
        }
        int idx = blockIdx.x * 256 + threadIdx.x;
        if (idx >= nimg * AREA * 36) return;
        int a = idx & (AREA - 1);
        int rest = idx >> 12;
        int oct = rest % 36;
        int n = rest / 36;
        const float* s = src + ((long)n * 288 + oct * 8) * AREA + a;
        uint4 u;
        u.x = bf16_rn(s[0])        | (bf16_rn(s[AREA])     << 16);
        u.y = bf16_rn(s[2 * AREA]) | (bf16_rn(s[3 * AREA]) << 16);
        u.z = bf16_rn(s[4 * AREA]) | (bf16_rn(s[5 * AREA]) << 16);
        u.w = bf16_rn(s[6 * AREA]) | (bf16_rn(s[7 * AREA]) << 16);
        *(uint4*)(dst + ((long)n * AREA + a) * 144 + oct * 4) = u;
    } else {
        int gw = blockIdx.x * 4 + (threadIdx.x >> 6);
        if (gw >= 1134) return;
        int lane = threadIdx.x & 63;
        const float* W; int Cin, KS, local, off;
        if      (gw < 162) { W = Wq; Cin = 288; KS = 9;  local = gw;       off = OFF_Q; }
        else if (gw < 324) { W = Wk; Cin = 288; KS = 9;  local = gw - 162; off = OFF_K; }
        else if (gw < 486) { W = Wv; Cin = 288; KS = 9;  local = gw - 324; off = OFF_V; }
        else if (gw < 810) { W = W1; Cin = 288; KS = 9;  local = gw - 486; off = OFF_1; }
        else               { W = W2; Cin = 576; KS = 18; local = gw - 810; off = OFF_2; }
        int ot = local / KS, ks = local - ot * KS;
        int o = ot * 16 + (lane & 15);
        int c0 = ks * 32 + ((lane >> 4) << 3);
        const float4* wr = (const float4*)(W + (long)o * Cin + c0);
        float4 f0 = wr[0], f1 = wr[1];
        uint4 u;
        u.x = bf16_rn(f0.x) | (bf16_rn(f0.y) << 16);
        u.y = bf16_rn(f0.z) | (bf16_rn(f0.w) << 16);
        u.z = bf16_rn(f1.x) | (bf16_rn(f1.y) << 16);
        u.w = bf16_rn(f1.z) | (bf16_rn(f1.w) << 16);
        wp[(long)off + (long)local * 64 + lane] = u;
    }
}

// ---- fused q/k/v MFMA projection ----------------------------------------
// z 0..1: q -> qpl plane-major [(b*12+g)*12 + d/2][a]
// z 2..5: k -> kpl plane-major [((b*2+c)*12+g)*12 + d/2][a]
// z 6..9: v -> v_u site-major [(n*12+g)][a][12 u32]
__global__ __launch_bounds__(256) void proj_qkv(
    const unsigned* __restrict__ xq, const unsigned* __restrict__ xk,
    const unsigned* __restrict__ xv, const uint4* __restrict__ wp,
    const float* __restrict__ bq, const float* __restrict__ bk,
    const float* __restrict__ bv, unsigned* __restrict__ qpl,
    unsigned* __restrict__ kpl, unsigned* __restrict__ v_u)
{
    const int z = blockIdx.z;
    const unsigned* Xt; const uint4* Wp; const float* bias;
    int outmode, n;
    if (z < 2)      { Xt = xq; Wp = wp + OFF_Q; bias = bq; outmode = 0; n = z; }
    else if (z < 6) { Xt = xk; Wp = wp + OFF_K; bias = bk; outmode = 1; n = z - 2; }
    else            { Xt = xv; Wp = wp + OFF_V; bias = bv; outmode = 2; n = z - 6; }

    const int tid = threadIdx.x;
    const int lane = tid & 63;
    const int w = tid >> 6;
    const int ot0 = blockIdx.y * 2;
    const int pw = blockIdx.x * 256 + w * 64;
    const int lcol = lane & 15;
    const int lrow = lane >> 4;

    const uint4* xrow[4];
#pragma unroll
    for (int s = 0; s < 4; ++s)
        xrow[s] = (const uint4*)(Xt + ((long)n * AREA + pw + s * 16 + lcol) * 144);
    const uint4* wa0 = Wp + (long)ot0 * 9 * 64 + lane;
    const uint4* wa1 = Wp + (long)(ot0 + 1) * 9 * 64 + lane;

    f32x4 acc[2][4];
#pragma unroll
    for (int m = 0; m < 2; ++m)
#pragma unroll
        for (int s = 0; s < 4; ++s) acc[m][s] = (f32x4){0.f, 0.f, 0.f, 0.f};

    for (int ks = 0; ks < 9; ++ks) {
        uint4 a0 = wa0[(long)ks * 64];
        uint4 a1 = wa1[(long)ks * 64];
        uint4 b[4];
#pragma unroll
        for (int s = 0; s < 4; ++s) b[s] = xrow[s][ks * 4 + lrow];
        short8 A0 = __builtin_bit_cast(short8, a0);
        short8 A1 = __builtin_bit_cast(short8, a1);
#pragma unroll
        for (int s = 0; s < 4; ++s) {
            short8 B = __builtin_bit_cast(short8, b[s]);
            acc[0][s] = __builtin_amdgcn_mfma_f32_16x16x32_bf16(A0, B, acc[0][s], 0, 0, 0);
            acc[1][s] = __builtin_amdgcn_mfma_f32_16x16x32_bf16(A1, B, acc[1][s], 0, 0, 0);
        }
    }

#pragma unroll
    for (int m = 0; m < 2; ++m) {
        const int obase = (ot0 + m) * 16 + lrow * 4;
        const float b0 = bias[obase], b1 = bias[obase + 1];
        const float b2 = bias[obase + 2], b3 = bias[obase + 3];
#pragma unroll
        for (int s = 0; s < 4; ++s) {
            const int pcol = pw + s * 16 + lcol;
            f32x4 a = acc[m][s];
            float v0 = a[0] + b0, v1 = a[1] + b1, v2 = a[2] + b2, v3 = a[3] + b3;
            uint2 st;
            st.x = bf16_rn(v0) | (bf16_rn(v1) << 16);
            st.y = bf16_rn(v2) | (bf16_rn(v3) << 16);
            int g = obase / 24, d0 = obase % 24;
            if (outmode == 0) {
                unsigned* base = qpl + ((long)(n * 12 + g) * 12 + (d0 >> 1)) * AREA + pcol;
                base[0] = st.x;
                base[AREA] = st.y;
            } else if (outmode == 1) {
                unsigned* base = kpl + ((long)(n * 12 + g) * 12 + (d0 >> 1)) * AREA + pcol;
                base[0] = st.x;
                base[AREA] = st.y;
            } else {
                *(uint2*)(v_u + ((long)(n * 12 + g) * AREA + pcol) * 12 + (d0 >> 1)) = st;
            }
        }
    }
}

// ---- FFN MFMA projection (unchanged) ------------------------------------
template<int OUT>
__global__ __launch_bounds__(256) void proj_mfma(
    const unsigned* __restrict__ Xt, const uint4* __restrict__ Wp,
    const float* __restrict__ bias, void* __restrict__ outp,
    const float* __restrict__ res, int KS, int RSu)
{
    const int tid = threadIdx.x;
    const int lane = tid & 63;
    const int w = tid >> 6;
    const int n = blockIdx.z;
    const int ot0 = blockIdx.y * 2;
    const int pw = blockIdx.x * 256 + w * 64;
    const int lcol = lane & 15;
    const int lrow = lane >> 4;

    const uint4* xrow[4];
#pragma unroll
    for (int s = 0; s < 4; ++s)
        xrow[s] = (const uint4*)(Xt + ((long)n * AREA + pw + s * 16 + lcol) * RSu);
    const uint4* wa0 = Wp + (long)ot0 * KS * 64 + lane;
    const uint4* wa1 = Wp + (long)(ot0 + 1) * KS * 64 + lane;

    f32x4 acc[2][4];
#pragma unroll
    for (int m = 0; m < 2; ++m)
#pragma unroll
        for (int s = 0; s < 4; ++s) acc[m][s] = (f32x4){0.f, 0.f, 0.f, 0.f};

    for (int ks = 0; ks < KS; ++ks) {
        uint4 a0 = wa0[(long)ks * 64];
        uint4 a1 = wa1[(long)ks * 64];
        uint4 b[4];
#pragma unroll
        for (int s = 0; s < 4; ++s) b[s] = xrow[s][ks * 4 + lrow];
        short8 A0 = __builtin_bit_cast(short8, a0);
        short8 A1 = __builtin_bit_cast(short8, a1);
#pragma unroll
        for (int s = 0; s < 4; ++s) {
            short8 B = __builtin_bit_cast(short8, b[s]);
            acc[0][s] = __builtin_amdgcn_mfma_f32_16x16x32_bf16(A0, B, acc[0][s], 0, 0, 0);
            acc[1][s] = __builtin_amdgcn_mfma_f32_16x16x32_bf16(A1, B, acc[1][s], 0, 0, 0);
        }
    }

#pragma unroll
    for (int m = 0; m < 2; ++m) {
        const int obase = (ot0 + m) * 16 + lrow * 4;
        const float b0 = bias[obase], b1 = bias[obase + 1];
        const float b2 = bias[obase + 2], b3 = bias[obase + 3];
#pragma unroll
        for (int s = 0; s < 4; ++s) {
            const int pcol = pw + s * 16 + lcol;
            f32x4 a = acc[m][s];
            float v0 = a[0] + b0, v1 = a[1] + b1, v2 = a[2] + b2, v3 = a[3] + b3;
            if (OUT == 3) {
                v0 = gelu_f(v0); v1 = gelu_f(v1); v2 = gelu_f(v2); v3 = gelu_f(v3);
                uint2 st;
                st.x = bf16_rn(v0) | (bf16_rn(v1) << 16);
                st.y = bf16_rn(v2) | (bf16_rn(v3) << 16);
                *(uint2*)((unsigned*)outp + ((long)n * AREA + pcol) * 288 + (obase >> 1)) = st;
            } else {
                float* fb = (float*)outp;
                float vals[4] = {v0, v1, v2, v3};
#pragma unroll
                for (int r = 0; r < 4; ++r) {
                    long addr = ((long)n * 288 + obase + r) * AREA + pcol;
                    fb[addr] = vals[r] + res[addr];
                }
            }
        }
    }
}

// ---- attn phase A: quarter-channel partial logits via LDS K planes ------
// 768 blocks = 48 slabs x 4 quarters x 4 chunks (XCD swizzled); 1024 thr;
// 48KB LDS (stride-3 u32, coprime to 32 banks) -> 2 blocks/CU.
__global__ __launch_bounds__(1024) void attn_logits(
    const unsigned* __restrict__ qpl, const unsigned* __restrict__ kpl,
    const float* __restrict__ offs, unsigned short* __restrict__ lgh)
{
    __shared__ unsigned kl[AREA * 3];
    const int bid = blockIdx.x;                       // 768 = 8*96
    const int lid = (bid & 7) * 96 + (bid >> 3);
    const int slab = lid >> 4;                        // (b*2+clip)*12+g
    const int rem = lid & 15;
    const int qt = rem >> 2;
    const int chunk = rem & 3;
    const int g = slab % 12;
    const int bc = slab / 12;
    const int b = bc >> 1, clip = bc & 1;
    const int tid = threadIdx.x;

    // stage 3 K planes (fully coalesced uint4 reads)
    const unsigned* kp = kpl + ((long)slab * 12 + qt * 3) * AREA;
#pragma unroll
    for (int j = 0; j < 3; ++j) {
        uint4 w = *(const uint4*)(kp + (long)j * AREA + tid * 4);
        kl[(tid * 4 + 0) * 3 + j] = w.x;
        kl[(tid * 4 + 1) * 3 + j] = w.y;
        kl[(tid * 4 + 2) * 3 + j] = w.z;
        kl[(tid * 4 + 3) * 3 + j] = w.w;
    }
    __syncthreads();

    const int a = chunk * 1024 + tid;
    const int py = a >> 6, px = a & 63;
    const float scale = 0.20412414523193150818f;      // 1/sqrt(24)
    float qv[6];
    const unsigned* qb = qpl + ((long)(b * 12 + g) * 12 + qt * 3) * AREA + a;
#pragma unroll
    for (int j = 0; j < 3; ++j) {
        unsigned u = qb[(long)j * AREA];
        qv[2 * j]     = bflo(u) * scale;
        qv[2 * j + 1] = bfhi(u) * scale;
    }
    const float* ob = offs + ((long)b * 432 + (clip * 12 + g) * 18) * AREA + a;
    unsigned short* lout = lgh + ((long)(slab * 4 + qt) * 9) * AREA + a;

#pragma unroll 3
    for (int k = 0; k < 9; ++k) {
        float oy = ob[(long)(2 * k) * AREA];
        float ox = ob[(long)(2 * k + 1) * AREA];
        int idx4[4]; float w4[4];
        bilin(k, py, px, oy, ox, idx4, w4);
        float s = 0.f;
#pragma unroll
        for (int c = 0; c < 4; ++c) {
            const unsigned* kc = &kl[idx4[c] * 3];
            unsigned u0 = kc[0], u1 = kc[1], u2 = kc[2];
            float d = qv[0] * bflo(u0) + qv[1] * bfhi(u0)
                    + qv[2] * bflo(u1) + qv[3] * bfhi(u1)
                    + qv[4] * bflo(u2) + qv[5] * bfhi(u2);
            s = fmaf(w4[c], d, s);
        }
        lout[(long)k * AREA] = __builtin_bit_cast(unsigned short, (_Float16)s);
    }
}

// ---- attn phase B: softmax (merge 4 quarter-partials) + V sum -----------
__global__ __launch_bounds__(256) void attn_vsum(
    const unsigned* __restrict__ v_u, const unsigned short* __restrict__ lgh,
    const float* __restrict__ offs, float* __restrict__ o,
    unsigned* __restrict__ ot)
{
    const int bid = blockIdx.x;                       // 768 = 8*96
    const int swz = (bid & 7) * 96 + (bid >> 3);
    const int t = swz * 256 + threadIdx.x;
    const int clip = t & 1;
    const int site = t >> 1;
    const int a = site & (AREA - 1);
    const int g = (site >> 12) % 12;
    const int b = site / (12 * AREA);
    const int py = a >> 6, px = a & 63;

    const int slab = (b * 2 + clip) * 12 + g;
    const unsigned short* lb = lgh + ((long)slab * 4 * 9) * AREA + a;
    float s9[9];
    float m9 = -1e30f;
#pragma unroll
    for (int k = 0; k < 9; ++k) {
        float s = (float)__builtin_bit_cast(_Float16, lb[(long)(0 * 9 + k) * AREA])
                + (float)__builtin_bit_cast(_Float16, lb[(long)(1 * 9 + k) * AREA])
                + (float)__builtin_bit_cast(_Float16, lb[(long)(2 * 9 + k) * AREA])
                + (float)__builtin_bit_cast(_Float16, lb[(long)(3 * 9 + k) * AREA]);
        s9[k] = s;
        m9 = fmaxf(m9, s);
    }
    float l9 = 0.f;
#pragma unroll
    for (int k = 0; k < 9; ++k) { s9[k] = __expf(s9[k] - m9); l9 += s9[k]; }
    float mo = __shfl_xor(m9, 1);
    float lo = __shfl_xor(l9, 1);
    float M = fmaxf(m9, mo);
    float fs = __expf(m9 - M);
    float l = l9 * fs + lo * __expf(mo - M);
    float winv = fs / l;          // w_k = s9[k] * winv

    float outv[24];
#pragma unroll
    for (int d = 0; d < 24; ++d) outv[d] = 0.f;

    const unsigned* vb = v_u + (long)((b * 2 + clip) * 12 + g) * AREA * 12;
    const float* ob = offs + ((long)b * 432 + (clip * 12 + g) * 18) * AREA + a;
#pragma unroll 3
    for (int k = 0; k < 9; ++k) {
        float oy = ob[(long)(2 * k) * AREA];
        float ox = ob[(long)(2 * k + 1) * AREA];
        int idx4[4]; float w4[4];
        bilin(k, py, px, oy, ox, idx4, w4);
        float wk = s9[k] * winv;
#pragma unroll
        for (int c = 0; c < 4; ++c) {
            const uint4* pc = (const uint4*)(vb + (long)idx4[c] * 12);
            uint4 u0 = pc[0], u1 = pc[1], u2 = pc[2];
            unsigned uu[12] = {u0.x, u0.y, u0.z, u0.w,
                               u1.x, u1.y, u1.z, u1.w,
                               u2.x, u2.y, u2.z, u2.w};
            float wc = wk * w4[c];
#pragma unroll
            for (int j = 0; j < 12; ++j) {
                outv[2 * j]     = fmaf(wc, bflo(uu[j]), outv[2 * j]);
                outv[2 * j + 1] = fmaf(wc, bfhi(uu[j]), outv[2 * j + 1]);
            }
        }
    }
#pragma unroll
    for (int d = 0; d < 24; ++d) outv[d] += __shfl_xor(outv[d], 1);

    if (clip == 0) {
#pragma unroll
        for (int d = 0; d < 24; ++d)
            o[((long)b * 288 + g * 24 + d) * AREA + a] = outv[d];
        unsigned* tb = ot + ((long)b * AREA + a) * 144 + g * 12;
        uint4 s0, s1, s2;
        s0.x = bf16_rn(outv[0])  | (bf16_rn(outv[1])  << 16);
        s0.y = bf16_rn(outv[2])  | (bf16_rn(outv[3])  << 16);
        s0.z = bf16_rn(outv[4])  | (bf16_rn(outv[5])  << 16);
        s0.w = bf16_rn(outv[6])  | (bf16_rn(outv[7])  << 16);
        s1.x = bf16_rn(outv[8])  | (bf16_rn(outv[9])  << 16);
        s1.y = bf16_rn(outv[10]) | (bf16_rn(outv[11]) << 16);
        s1.z = bf16_rn(outv[12]) | (bf16_rn(outv[13]) << 16);
        s1.w = bf16_rn(outv[14]) | (bf16_rn(outv[15]) << 16);
        s2.x = bf16_rn(outv[16]) | (bf16_rn(outv[17]) << 16);
        s2.y = bf16_rn(outv[18]) | (bf16_rn(outv[19]) << 16);
        s2.z = bf16_rn(outv[20]) | (bf16_rn(outv[21]) << 16);
        s2.w = bf16_rn(outv[22]) | (bf16_rn(outv[23]) << 16);
        ((uint4*)tb)[0] = s0; ((uint4*)tb)[1] = s1; ((uint4*)tb)[2] = s2;
    }
}

extern "C" void kernel_launch(void* const* d_in, const int* in_sizes, int n_in,
                              void* d_out, int out_size, void* d_ws, size_t ws_size,
                              hipStream_t stream) {
    const float* q      = (const float*)d_in[0];
    const float* k      = (const float*)d_in[1];
    const float* v      = (const float*)d_in[2];
    const float* offset = (const float*)d_in[3];
    const float* Wq     = (const float*)d_in[4];
    const float* bq     = (const float*)d_in[5];
    const float* Wk     = (const float*)d_in[6];
    const float* bk     = (const float*)d_in[7];
    const float* Wv     = (const float*)d_in[8];
    const float* bv     = (const float*)d_in[9];
    const float* W1     = (const float*)d_in[10];
    const float* b1     = (const float*)d_in[11];
    const float* W2     = (const float*)d_in[12];
    const float* b2     = (const float*)d_in[13];
    float* out = (float*)d_out;
    float* ws  = (float*)d_ws;

    // ws layout (u32 units); peak 13,266,432 u32 = 53.1 MB (same as R10)
    unsigned* qpl = (unsigned*)ws;                     //  0        (1,179,648)
    unsigned* kpl = (unsigned*)(ws + 1179648);         //           (2,359,296)
    unsigned* v_u = (unsigned*)(ws + 3538944);         //           (2,359,296)
    unsigned* xq  = (unsigned*)(ws + 5898240);         //           (1,179,648)
    unsigned* xk  = (unsigned*)(ws + 7077888);         //           (2,359,296)
    unsigned* xv  = (unsigned*)(ws + 9437184);         //           (2,359,296)
    uint4*    wp  = (uint4*)(ws + 11796480);           //           (290,304)
    unsigned* o_t = (unsigned*)(ws + 12086784);        //           (1,179,648)
    unsigned short* lgh = (unsigned short*)(ws + 5898240); // alias xq+xk (7,077,888 u16)
    unsigned* x1  = xv;                                // alias xv (after vsum)

    // 1) transpose inputs + pack weights
    prep_kernel<<<dim3(2304, 4), dim3(256), 0, stream>>>(
        q, k, v, Wq, Wk, Wv, W1, W2, xq, xk, xv, wp);
    // 2) fused q/k/v projections (q,k plane-major; v site-major)
    proj_qkv<<<dim3(16, 9, 10), dim3(256), 0, stream>>>(
        xq, xk, xv, wp, bq, bk, bv, qpl, kpl, v_u);
    // 3a) attn phase A: quarter-channel partial logits (LDS K planes)
    attn_logits<<<dim3(768), dim3(1024), 0, stream>>>(qpl, kpl, offset, lgh);
    // 3b) attn phase B: softmax + V sum -> d_out (f32) + o_t (bf16 site-major)
    attn_vsum<<<dim3(768), dim3(256), 0, stream>>>(v_u, lgh, offset, out, o_t);
    // 4) FFN1: o_t(288) -> x1(576) bf16 site-major, GELU
    proj_mfma<3><<<dim3(16, 18, 2), dim3(256), 0, stream>>>(
        o_t, wp + OFF_1, b1, x1, nullptr, 9, 144);
    // 5) FFN2: x1(576) -> d_out f32 chan-major + residual o
    proj_mfma<0><<<dim3(16, 9, 2), dim3(256), 0, stream>>>(
        x1, wp + OFF_2, b2, out, out, 18, 288);
}

// Round 12
// 136.752 us; speedup vs baseline: 1.2095x; 1.0752x over previous
//
#include <hip/hip_runtime.h>

#define AREA 4096

typedef short short8 __attribute__((ext_vector_type(8)));
typedef float f32x4 __attribute__((ext_vector_type(4)));

__device__ __forceinline__ unsigned bf16_rn(float x) {
    unsigned u = __builtin_bit_cast(unsigned, x);
    u += 0x7fffu + ((u >> 16) & 1u);
    return u >> 16;
}
__device__ __forceinline__ float bflo(unsigned u) { return __builtin_bit_cast(float, u << 16); }
__device__ __forceinline__ float bfhi(unsigned u) { return __builtin_bit_cast(float, u & 0xffff0000u); }
__device__ __forceinline__ float gelu_f(float x) {
    return 0.5f * x * (1.f + erff(x * 0.70710678118654752f));
}

// W-frag tile offsets (in uint4 units)
#define OFF_Q 0
#define OFF_K (162 * 64)
#define OFF_V (324 * 64)
#define OFF_1 (486 * 64)
#define OFF_2 (810 * 64)

// ---- prep: y=0/1/2 transpose q/k/v to pixel-major bf16; y=3 pack weights --
__global__ __launch_bounds__(256) void prep_kernel(
    const float* __restrict__ q, const float* __restrict__ k,
    const float* __restrict__ v,
    const float* __restrict__ Wq, const float* __restrict__ Wk,
    const float* __restrict__ Wv, const float* __restrict__ W1,
    const float* __restrict__ W2,
    unsigned* __restrict__ xq, unsigned* __restrict__ xk,
    unsigned* __restrict__ xv, uint4* __restrict__ wp)
{
    if (blockIdx.y < 3) {
        const float* src; unsigned* dst; int nimg;
        switch (blockIdx.y) {
            case 0: src = q; dst = xq; nimg = 2; break;
            case 1: src = k; dst = xk; nimg = 4; break;
            default:src = v; dst = xv; nimg = 4; break;
        }
        int idx = blockIdx.x * 256 + threadIdx.x;
        if (idx >= nimg * AREA * 36) return;
        int a = idx & (AREA - 1);
        int rest = idx >> 12;
        int oct = rest % 36;
        int n = rest / 36;
        const float* s = src + ((long)n * 288 + oct * 8) * AREA + a;
        uint4 u;
        u.x = bf16_rn(s[0])        | (bf16_rn(s[AREA])     << 16);
        u.y = bf16_rn(s[2 * AREA]) | (bf16_rn(s[3 * AREA]) << 16);
        u.z = bf16_rn(s[4 * AREA]) | (bf16_rn(s[5 * AREA]) << 16);
        u.w = bf16_rn(s[6 * AREA]) | (bf16_rn(s[7 * AREA]) << 16);
        *(uint4*)(dst + ((long)n * AREA + a) * 144 + oct * 4) = u;
    } else {
        int gw = blockIdx.x * 4 + (threadIdx.x >> 6);
        if (gw >= 1134) return;
        int lane = threadIdx.x & 63;
        const float* W; int Cin, KS, local, off;
        if      (gw < 162) { W = Wq; Cin = 288; KS = 9;  local = gw;       off = OFF_Q; }
        else if (gw < 324) { W = Wk; Cin = 288; KS = 9;  local = gw - 162; off = OFF_K; }
        else if (gw < 486) { W = Wv; Cin = 288; KS = 9;  local = gw - 324; off = OFF_V; }
        else if (gw < 810) { W = W1; Cin = 288; KS = 9;  local = gw - 486; off = OFF_1; }
        else               { W = W2; Cin = 576; KS = 18; local = gw - 810; off = OFF_2; }
        int ot = local / KS, ks = local - ot * KS;
        int o = ot * 16 + (lane & 15);
        int c0 = ks * 32 + ((lane >> 4) << 3);
        const float4* wr = (const float4*)(W + (long)o * Cin + c0);
        float4 f0 = wr[0], f1 = wr[1];
        uint4 u;
        u.x = bf16_rn(f0.x) | (bf16_rn(f0.y) << 16);
        u.y = bf16_rn(f0.z) | (bf16_rn(f0.w) << 16);
        u.z = bf16_rn(f1.x) | (bf16_rn(f1.y) << 16);
        u.w = bf16_rn(f1.z) | (bf16_rn(f1.w) << 16);
        wp[(long)off + (long)local * 64 + lane] = u;
    }
}

// ---- fused q/k/v MFMA projection, 6 out-tiles per block ------------------
// z 0..1: q -> qp_u (bf16 site-major [n*A+a][144 u32])
// z 2..5: k -> kv_u[..., 0:12]; z 6..9: v -> kv_u[..., 12:24]
__global__ __launch_bounds__(256) void proj_qkv(
    const unsigned* __restrict__ xq, const unsigned* __restrict__ xk,
    const unsigned* __restrict__ xv, const uint4* __restrict__ wp,
    const float* __restrict__ bq, const float* __restrict__ bk,
    const float* __restrict__ bv, unsigned* __restrict__ qp_u,
    unsigned* __restrict__ kv_u)
{
    const int z = blockIdx.z;
    const unsigned* Xt; const uint4* Wp; const float* bias;
    int outmode, voff, n;
    if (z < 2)      { Xt = xq; Wp = wp + OFF_Q; bias = bq; outmode = 1; voff = 0;  n = z; }
    else if (z < 6) { Xt = xk; Wp = wp + OFF_K; bias = bk; outmode = 2; voff = 0;  n = z - 2; }
    else            { Xt = xv; Wp = wp + OFF_V; bias = bv; outmode = 2; voff = 12; n = z - 6; }

    const int tid = threadIdx.x;
    const int lane = tid & 63;
    const int w = tid >> 6;
    const int ot0 = blockIdx.y * 6;
    const int pw = blockIdx.x * 256 + w * 64;
    const int lcol = lane & 15;
    const int lrow = lane >> 4;

    const uint4* xrow[4];
#pragma unroll
    for (int s = 0; s < 4; ++s)
        xrow[s] = (const uint4*)(Xt + ((long)n * AREA + pw + s * 16 + lcol) * 144);
    const uint4* wa[6];
#pragma unroll
    for (int m = 0; m < 6; ++m)
        wa[m] = Wp + (long)(ot0 + m) * 9 * 64 + lane;

    f32x4 acc[6][4];
#pragma unroll
    for (int m = 0; m < 6; ++m)
#pragma unroll
        for (int s = 0; s < 4; ++s) acc[m][s] = (f32x4){0.f, 0.f, 0.f, 0.f};

    for (int ks = 0; ks < 9; ++ks) {
        short8 A[6];
#pragma unroll
        for (int m = 0; m < 6; ++m)
            A[m] = __builtin_bit_cast(short8, wa[m][(long)ks * 64]);
#pragma unroll
        for (int s = 0; s < 4; ++s) {
            short8 B = __builtin_bit_cast(short8, xrow[s][ks * 4 + lrow]);
#pragma unroll
            for (int m = 0; m < 6; ++m)
                acc[m][s] = __builtin_amdgcn_mfma_f32_16x16x32_bf16(A[m], B, acc[m][s], 0, 0, 0);
        }
    }

#pragma unroll
    for (int m = 0; m < 6; ++m) {
        const int obase = (ot0 + m) * 16 + lrow * 4;
        const float b0 = bias[obase], b1 = bias[obase + 1];
        const float b2 = bias[obase + 2], b3 = bias[obase + 3];
#pragma unroll
        for (int s = 0; s < 4; ++s) {
            const int pcol = pw + s * 16 + lcol;
            f32x4 a = acc[m][s];
            float v0 = a[0] + b0, v1 = a[1] + b1, v2 = a[2] + b2, v3 = a[3] + b3;
            uint2 st;
            st.x = bf16_rn(v0) | (bf16_rn(v1) << 16);
            st.y = bf16_rn(v2) | (bf16_rn(v3) << 16);
            if (outmode == 1) {
                *(uint2*)(qp_u + ((long)n * AREA + pcol) * 144 + (obase >> 1)) = st;
            } else {
                int g = obase / 24, d0 = obase % 24;
                *(uint2*)(kv_u + ((long)(n * 12 + g) * AREA + pcol) * 24 + voff + (d0 >> 1)) = st;
            }
        }
    }
}

// ---- FFN MFMA projection, 6 out-tiles per block --------------------------
// OUT 0: f32 chan-major + residual (FFN2)   OUT 3: bf16 site-major + GELU
template<int OUT>
__global__ __launch_bounds__(256) void proj_mfma(
    const unsigned* __restrict__ Xt, const uint4* __restrict__ Wp,
    const float* __restrict__ bias, void* __restrict__ outp,
    const float* __restrict__ res, int KS, int RSu)
{
    const int tid = threadIdx.x;
    const int lane = tid & 63;
    const int w = tid >> 6;
    const int n = blockIdx.z;
    const int ot0 = blockIdx.y * 6;
    const int pw = blockIdx.x * 256 + w * 64;
    const int lcol = lane & 15;
    const int lrow = lane >> 4;

    const uint4* xrow[4];
#pragma unroll
    for (int s = 0; s < 4; ++s)
        xrow[s] = (const uint4*)(Xt + ((long)n * AREA + pw + s * 16 + lcol) * RSu);
    const uint4* wa[6];
#pragma unroll
    for (int m = 0; m < 6; ++m)
        wa[m] = Wp + (long)(ot0 + m) * KS * 64 + lane;

    f32x4 acc[6][4];
#pragma unroll
    for (int m = 0; m < 6; ++m)
#pragma unroll
        for (int s = 0; s < 4; ++s) acc[m][s] = (f32x4){0.f, 0.f, 0.f, 0.f};

    for (int ks = 0; ks < KS; ++ks) {
        short8 A[6];
#pragma unroll
        for (int m = 0; m < 6; ++m)
            A[m] = __builtin_bit_cast(short8, wa[m][(long)ks * 64]);
#pragma unroll
        for (int s = 0; s < 4; ++s) {
            short8 B = __builtin_bit_cast(short8, xrow[s][ks * 4 + lrow]);
#pragma unroll
            for (int m = 0; m < 6; ++m)
                acc[m][s] = __builtin_amdgcn_mfma_f32_16x16x32_bf16(A[m], B, acc[m][s], 0, 0, 0);
        }
    }

#pragma unroll
    for (int m = 0; m < 6; ++m) {
        const int obase = (ot0 + m) * 16 + lrow * 4;
        const float b0 = bias[obase], b1 = bias[obase + 1];
        const float b2 = bias[obase + 2], b3 = bias[obase + 3];
#pragma unroll
        for (int s = 0; s < 4; ++s) {
            const int pcol = pw + s * 16 + lcol;
            f32x4 a = acc[m][s];
            float v0 = a[0] + b0, v1 = a[1] + b1, v2 = a[2] + b2, v3 = a[3] + b3;
            if (OUT == 3) {
                v0 = gelu_f(v0); v1 = gelu_f(v1); v2 = gelu_f(v2); v3 = gelu_f(v3);
                uint2 st;
                st.x = bf16_rn(v0) | (bf16_rn(v1) << 16);
                st.y = bf16_rn(v2) | (bf16_rn(v3) << 16);
                *(uint2*)((unsigned*)outp + ((long)n * AREA + pcol) * 288 + (obase >> 1)) = st;
            } else {
                float* fb = (float*)outp;
                float vals[4] = {v0, v1, v2, v3};
#pragma unroll
                for (int r = 0; r < 4; ++r) {
                    long addr = ((long)n * 288 + obase + r) * AREA + pcol;
                    fb[addr] = vals[r] + res[addr];
                }
            }
        }
    }
}

// ---------------- deformable attention (R8 fused version) ----------------
// 4 lanes/site: bit0 = role (K/V), bit1 = clip partition; XCD swizzle.
__global__ __launch_bounds__(256) void deform_attn_kernel(
    const unsigned* __restrict__ qp, const unsigned* __restrict__ kv,
    const float* __restrict__ offs, float* __restrict__ o,
    unsigned* __restrict__ ot)
{
    const int bid = blockIdx.x;
    const int swz = (bid & 7) * 192 + (bid >> 3);    // 1536 = 8 * 192, bijective
    const int t = swz * 256 + threadIdx.x;
    const int role = t & 1;
    const int clip = (t >> 1) & 1;
    const int site = t >> 2;                 // (b*12 + g)*A + a
    const int a = site & (AREA - 1);
    const int g = (site >> 12) % 12;
    const int b = site / (12 * AREA);
    const int py = a >> 6, px = a & 63;
    const float scale = 0.20412414523193150818f;   // 1/sqrt(24)

    float qv[24];
    {
        const uint4* qb = (const uint4*)(qp + ((long)b * AREA + a) * 144 + g * 12);
        uint4 q0 = qb[0], q1 = qb[1], q2 = qb[2];
        unsigned uq[12] = {q0.x, q0.y, q0.z, q0.w, q1.x, q1.y, q1.z, q1.w,
                           q2.x, q2.y, q2.z, q2.w};
#pragma unroll
        for (int j = 0; j < 12; ++j) {
            qv[2 * j]     = bflo(uq[j]) * scale;
            qv[2 * j + 1] = bfhi(uq[j]) * scale;
        }
    }

    float m = -1e30f, l = 0.f;
    float outv[24];
#pragma unroll
    for (int d = 0; d < 24; ++d) outv[d] = 0.f;

    const unsigned* __restrict__ cb =
        kv + (long)((b * 2 + clip) * 12 + g) * AREA * 24 + role * 12;
    const float* __restrict__ obase =
        offs + ((long)b * 432 + (clip * 12 + g) * 18) * AREA;
#pragma unroll 3
    for (int k = 0; k < 9; ++k) {
        float oy = obase[(long)(2 * k) * AREA + a];
        float ox = obase[(long)(2 * k + 1) * AREA + a];
        int ky = k / 3, kx = k - ky * 3;
        float ys = (float)(py + ky - 1) + oy;
        float xs_ = (float)(px + kx - 1) + ox;
        float y0f = floorf(ys), x0f = floorf(xs_);
        float dy = ys - y0f, dx = xs_ - x0f;
        float wy[2] = {1.f - dy, dy};
        float wx[2] = {1.f - dx, dx};
        long  idx4[4];
        float w4[4];
#pragma unroll
        for (int cy = 0; cy < 2; ++cy) {
            float yc = y0f + (float)cy;
            bool vy = (yc >= 0.f) && (yc <= 63.f);
            int yi = (int)fminf(fmaxf(yc, 0.f), 63.f);
#pragma unroll
            for (int cx = 0; cx < 2; ++cx) {
                float xc = x0f + (float)cx;
                bool vx = (xc >= 0.f) && (xc <= 63.f);
                int xi = (int)fminf(fmaxf(xc, 0.f), 63.f);
                w4[cy * 2 + cx] = wy[cy] * wx[cx] * ((vy && vx) ? 1.f : 0.f);
                idx4[cy * 2 + cx] = (long)(yi * 64 + xi) * 24;
            }
        }
        float xs[24];
#pragma unroll
        for (int j = 0; j < 24; ++j) xs[j] = 0.f;
        float sh = 0.f;
#pragma unroll
        for (int c = 0; c < 4; ++c) {
            const uint4* pc = (const uint4*)(cb + idx4[c]);
            uint4 u0 = pc[0], u1 = pc[1], u2 = pc[2];
            unsigned uu[12] = {u0.x, u0.y, u0.z, u0.w,
                               u1.x, u1.y, u1.z, u1.w,
                               u2.x, u2.y, u2.z, u2.w};
            float w = w4[c];
            float d = 0.f;
#pragma unroll
            for (int j = 0; j < 12; ++j) {
                float lo = bflo(uu[j]), hi = bfhi(uu[j]);
                d = fmaf(qv[2 * j], lo, d);
                d = fmaf(qv[2 * j + 1], hi, d);
                xs[2 * j]     = fmaf(w, lo, xs[2 * j]);
                xs[2 * j + 1] = fmaf(w, hi, xs[2 * j + 1]);
            }
            sh = fmaf(w, d, sh);
        }
        float sx = __shfl_xor(sh, 1);
        float s = role ? sx : sh;          // K-lane's full dot
        float mn = fmaxf(m, s);
        float corr = __expf(m - mn);
        float p = __expf(s - mn);
        l = l * corr + p;
        m = mn;
#pragma unroll
        for (int j = 0; j < 24; ++j)
            outv[j] = fmaf(outv[j], corr, p * xs[j]);
    }

    // ---- merge the two clip partitions (lanes differing in bit 1) ----
    float mo  = __shfl_xor(m, 2);
    float lo2 = __shfl_xor(l, 2);
    float mn = fmaxf(m, mo);
    float fs = __expf(m - mn), fo = __expf(mo - mn);
    float lm = l * fs + lo2 * fo;
    float inv = 1.f / lm;
#pragma unroll
    for (int d = 0; d < 24; ++d) {
        float ovo = __shfl_xor(outv[d], 2);
        outv[d] = (outv[d] * fs + ovo * fo) * inv;
    }

    if (role == 1 && clip == 0) {
        float ov[24];
#pragma unroll
        for (int d = 0; d < 24; ++d) {
            ov[d] = outv[d];
            o[((long)b * 288 + g * 24 + d) * AREA + a] = ov[d];
        }
        unsigned* tb = ot + ((long)b * AREA + a) * 144 + g * 12;
        uint4 s0, s1, s2;
        s0.x = bf16_rn(ov[0])  | (bf16_rn(ov[1])  << 16);
        s0.y = bf16_rn(ov[2])  | (bf16_rn(ov[3])  << 16);
        s0.z = bf16_rn(ov[4])  | (bf16_rn(ov[5])  << 16);
        s0.w = bf16_rn(ov[6])  | (bf16_rn(ov[7])  << 16);
        s1.x = bf16_rn(ov[8])  | (bf16_rn(ov[9])  << 16);
        s1.y = bf16_rn(ov[10]) | (bf16_rn(ov[11]) << 16);
        s1.z = bf16_rn(ov[12]) | (bf16_rn(ov[13]) << 16);
        s1.w = bf16_rn(ov[14]) | (bf16_rn(ov[15]) << 16);
        s2.x = bf16_rn(ov[16]) | (bf16_rn(ov[17]) << 16);
        s2.y = bf16_rn(ov[18]) | (bf16_rn(ov[19]) << 16);
        s2.z = bf16_rn(ov[20]) | (bf16_rn(ov[21]) << 16);
        s2.w = bf16_rn(ov[22]) | (bf16_rn(ov[23]) << 16);
        ((uint4*)tb)[0] = s0; ((uint4*)tb)[1] = s1; ((uint4*)tb)[2] = s2;
    }
}

extern "C" void kernel_launch(void* const* d_in, const int* in_sizes, int n_in,
                              void* d_out, int out_size, void* d_ws, size_t ws_size,
                              hipStream_t stream) {
    const float* q      = (const float*)d_in[0];
    const float* k      = (const float*)d_in[1];
    const float* v      = (const float*)d_in[2];
    const float* offset = (const float*)d_in[3];
    const float* Wq     = (const float*)d_in[4];
    const float* bq     = (const float*)d_in[5];
    const float* Wk     = (const float*)d_in[6];
    const float* bk     = (const float*)d_in[7];
    const float* Wv     = (const float*)d_in[8];
    const float* bv     = (const float*)d_in[9];
    const float* W1     = (const float*)d_in[10];
    const float* b1     = (const float*)d_in[11];
    const float* W2     = (const float*)d_in[12];
    const float* b2     = (const float*)d_in[13];
    float* out = (float*)d_out;
    float* ws  = (float*)d_ws;

    unsigned* qp_u = (unsigned*)ws;                    // 1,179,648 u32
    unsigned* kv_u = (unsigned*)(ws + 2359296);        // 4,718,592 u32
    unsigned* xq   = (unsigned*)(ws + 7077888);        // 1,179,648 u32
    unsigned* xk   = (unsigned*)(ws + 8257536);        // 2,359,296 u32 (x1 aliases)
    unsigned* xv   = (unsigned*)(ws + 10616832);       // 2,359,296 u32 (o_t aliases)
    uint4*    wp   = (uint4*)(ws + 12976128);
    unsigned* x1   = xk;
    unsigned* o_t  = xv;

    // 1) transpose inputs + pack weights
    prep_kernel<<<dim3(2304, 4), dim3(256), 0, stream>>>(
        q, k, v, Wq, Wk, Wv, W1, W2, xq, xk, xv, wp);
    // 2) fused q/k/v projections (6 out-tiles/block)
    proj_qkv<<<dim3(16, 3, 10), dim3(256), 0, stream>>>(
        xq, xk, xv, wp, bq, bk, bv, qp_u, kv_u);
    // 3) deformable attention -> d_out (f32) + o_t (bf16 site-major)
    deform_attn_kernel<<<dim3(1536), dim3(256), 0, stream>>>(
        qp_u, kv_u, offset, out, o_t);
    // 4) FFN1: o_t(288) -> x1(576) bf16 site-major, GELU
    proj_mfma<3><<<dim3(16, 6, 2), dim3(256), 0, stream>>>(
        o_t, wp + OFF_1, b1, x1, nullptr, 9, 144);
    // 5) FFN2: x1(576) -> d_out f32 chan-major + residual o
    proj_mfma<0><<<dim3(16, 3, 2), dim3(256), 0, stream>>>(
        x1, wp + OFF_2, b2, out, out, 18, 288);
}

// Round 13
// 135.368 us; speedup vs baseline: 1.2219x; 1.0102x over previous
//
#include <hip/hip_runtime.h>

#define AREA 4096

typedef short short8 __attribute__((ext_vector_type(8)));
typedef float f32x4 __attribute__((ext_vector_type(4)));

__device__ __forceinline__ unsigned bf16_rn(float x) {
    unsigned u = __builtin_bit_cast(unsigned, x);
    u += 0x7fffu + ((u >> 16) & 1u);
    return u >> 16;
}
__device__ __forceinline__ float bflo(unsigned u) { return __builtin_bit_cast(float, u << 16); }
__device__ __forceinline__ float bfhi(unsigned u) { return __builtin_bit_cast(float, u & 0xffff0000u); }
__device__ __forceinline__ float gelu_f(float x) {
    return 0.5f * x * (1.f + erff(x * 0.70710678118654752f));
}

// W-frag tile offsets (in uint4 units)
#define OFF_Q 0
#define OFF_K (162 * 64)
#define OFF_V (324 * 64)
#define OFF_1 (486 * 64)
#define OFF_2 (810 * 64)

// ---- prep: y=0/1/2 transpose q/k/v to pixel-major bf16; y=3 pack weights --
__global__ __launch_bounds__(256) void prep_kernel(
    const float* __restrict__ q, const float* __restrict__ k,
    const float* __restrict__ v,
    const float* __restrict__ Wq, const float* __restrict__ Wk,
    const float* __restrict__ Wv, const float* __restrict__ W1,
    const float* __restrict__ W2,
    unsigned* __restrict__ xq, unsigned* __restrict__ xk,
    unsigned* __restrict__ xv, uint4* __restrict__ wp)
{
    if (blockIdx.y < 3) {
        const float* src; unsigned* dst; int nimg;
        switch (blockIdx.y) {
            case 0: src = q; dst = xq; nimg = 2; break;
            case 1: src = k; dst = xk; nimg = 4; break;
            default:src = v; dst = xv; nimg = 4; break;
        }
        int idx = blockIdx.x * 256 + threadIdx.x;
        if (idx >= nimg * AREA * 36) return;
        int a = idx & (AREA - 1);
        int rest = idx >> 12;
        int oct = rest % 36;
        int n = rest / 36;
        const float* s = src + ((long)n * 288 + oct * 8) * AREA + a;
        uint4 u;
        u.x = bf16_rn(s[0])        | (bf16_rn(s[AREA])     << 16);
        u.y = bf16_rn(s[2 * AREA]) | (bf16_rn(s[3 * AREA]) << 16);
        u.z = bf16_rn(s[4 * AREA]) | (bf16_rn(s[5 * AREA]) << 16);
        u.w = bf16_rn(s[6 * AREA]) | (bf16_rn(s[7 * AREA]) << 16);
        *(uint4*)(dst + ((long)n * AREA + a) * 144 + oct * 4) = u;
    } else {
        int gw = blockIdx.x * 4 + (threadIdx.x >> 6);
        if (gw >= 1134) return;
        int lane = threadIdx.x & 63;
        const float* W; int Cin, KS, local, off;
        if      (gw < 162) { W = Wq; Cin = 288; KS = 9;  local = gw;       off = OFF_Q; }
        else if (gw < 324) { W = Wk; Cin = 288; KS = 9;  local = gw - 162; off = OFF_K; }
        else if (gw < 486) { W = Wv; Cin = 288; KS = 9;  local = gw - 324; off = OFF_V; }
        else if (gw < 810) { W = W1; Cin = 288; KS = 9;  local = gw - 486; off = OFF_1; }
        else               { W = W2; Cin = 576; KS = 18; local = gw - 810; off = OFF_2; }
        int ot = local / KS, ks = local - ot * KS;
        int o = ot * 16 + (lane & 15);
        int c0 = ks * 32 + ((lane >> 4) << 3);
        const float4* wr = (const float4*)(W + (long)o * Cin + c0);
        float4 f0 = wr[0], f1 = wr[1];
        uint4 u;
        u.x = bf16_rn(f0.x) | (bf16_rn(f0.y) << 16);
        u.y = bf16_rn(f0.z) | (bf16_rn(f0.w) << 16);
        u.z = bf16_rn(f1.x) | (bf16_rn(f1.y) << 16);
        u.w = bf16_rn(f1.z) | (bf16_rn(f1.w) << 16);
        wp[(long)off + (long)local * 64 + lane] = u;
    }
}

// ---- fused q/k/v MFMA projection (2 out-tiles/block, R8 geometry) -------
// z 0..1: q -> qp_u (bf16 site-major); z 2..5: k -> kv_u[..,0:12];
// z 6..9: v -> kv_u[..,12:24]
__global__ __launch_bounds__(256) void proj_qkv(
    const unsigned* __restrict__ xq, const unsigned* __restrict__ xk,
    const unsigned* __restrict__ xv, const uint4* __restrict__ wp,
    const float* __restrict__ bq, const float* __restrict__ bk,
    const float* __restrict__ bv, unsigned* __restrict__ qp_u,
    unsigned* __restrict__ kv_u)
{
    const int z = blockIdx.z;
    const unsigned* Xt; const uint4* Wp; const float* bias;
    int outmode, voff, n;
    if (z < 2)      { Xt = xq; Wp = wp + OFF_Q; bias = bq; outmode = 1; voff = 0;  n = z; }
    else if (z < 6) { Xt = xk; Wp = wp + OFF_K; bias = bk; outmode = 2; voff = 0;  n = z - 2; }
    else            { Xt = xv; Wp = wp + OFF_V; bias = bv; outmode = 2; voff = 12; n = z - 6; }

    const int tid = threadIdx.x;
    const int lane = tid & 63;
    const int w = tid >> 6;
    const int ot0 = blockIdx.y * 2;
    const int pw = blockIdx.x * 256 + w * 64;
    const int lcol = lane & 15;
    const int lrow = lane >> 4;

    const uint4* xrow[4];
#pragma unroll
    for (int s = 0; s < 4; ++s)
        xrow[s] = (const uint4*)(Xt + ((long)n * AREA + pw + s * 16 + lcol) * 144);
    const uint4* wa0 = Wp + (long)ot0 * 9 * 64 + lane;
    const uint4* wa1 = Wp + (long)(ot0 + 1) * 9 * 64 + lane;

    f32x4 acc[2][4];
#pragma unroll
    for (int m = 0; m < 2; ++m)
#pragma unroll
        for (int s = 0; s < 4; ++s) acc[m][s] = (f32x4){0.f, 0.f, 0.f, 0.f};

    for (int ks = 0; ks < 9; ++ks) {
        uint4 a0 = wa0[(long)ks * 64];
        uint4 a1 = wa1[(long)ks * 64];
        uint4 b[4];
#pragma unroll
        for (int s = 0; s < 4; ++s) b[s] = xrow[s][ks * 4 + lrow];
        short8 A0 = __builtin_bit_cast(short8, a0);
        short8 A1 = __builtin_bit_cast(short8, a1);
#pragma unroll
        for (int s = 0; s < 4; ++s) {
            short8 B = __builtin_bit_cast(short8, b[s]);
            acc[0][s] = __builtin_amdgcn_mfma_f32_16x16x32_bf16(A0, B, acc[0][s], 0, 0, 0);
            acc[1][s] = __builtin_amdgcn_mfma_f32_16x16x32_bf16(A1, B, acc[1][s], 0, 0, 0);
        }
    }

#pragma unroll
    for (int m = 0; m < 2; ++m) {
        const int obase = (ot0 + m) * 16 + lrow * 4;
        const float b0 = bias[obase], b1 = bias[obase + 1];
        const float b2 = bias[obase + 2], b3 = bias[obase + 3];
#pragma unroll
        for (int s = 0; s < 4; ++s) {
            const int pcol = pw + s * 16 + lcol;
            f32x4 a = acc[m][s];
            float v0 = a[0] + b0, v1 = a[1] + b1, v2 = a[2] + b2, v3 = a[3] + b3;
            uint2 st;
            st.x = bf16_rn(v0) | (bf16_rn(v1) << 16);
            st.y = bf16_rn(v2) | (bf16_rn(v3) << 16);
            if (outmode == 1) {
                *(uint2*)(qp_u + ((long)n * AREA + pcol) * 144 + (obase >> 1)) = st;
            } else {
                int g = obase / 24, d0 = obase % 24;
                *(uint2*)(kv_u + ((long)(n * 12 + g) * AREA + pcol) * 24 + voff + (d0 >> 1)) = st;
            }
        }
    }
}

// ---- FFN MFMA projection ------------------------------------------------
// OUT 0: f32 chan-major + bf16 residual from o_t (FFN2)
// OUT 3: bf16 site-major + GELU (FFN1)
template<int OUT>
__global__ __launch_bounds__(256) void proj_mfma(
    const unsigned* __restrict__ Xt, const uint4* __restrict__ Wp,
    const float* __restrict__ bias, void* __restrict__ outp,
    const unsigned* __restrict__ res_u, int KS, int RSu)
{
    const int tid = threadIdx.x;
    const int lane = tid & 63;
    const int w = tid >> 6;
    const int n = blockIdx.z;
    const int ot0 = blockIdx.y * 2;
    const int pw = blockIdx.x * 256 + w * 64;
    const int lcol = lane & 15;
    const int lrow = lane >> 4;

    const uint4* xrow[4];
#pragma unroll
    for (int s = 0; s < 4; ++s)
        xrow[s] = (const uint4*)(Xt + ((long)n * AREA + pw + s * 16 + lcol) * RSu);
    const uint4* wa0 = Wp + (long)ot0 * KS * 64 + lane;
    const uint4* wa1 = Wp + (long)(ot0 + 1) * KS * 64 + lane;

    f32x4 acc[2][4];
#pragma unroll
    for (int m = 0; m < 2; ++m)
#pragma unroll
        for (int s = 0; s < 4; ++s) acc[m][s] = (f32x4){0.f, 0.f, 0.f, 0.f};

    for (int ks = 0; ks < KS; ++ks) {
        uint4 a0 = wa0[(long)ks * 64];
        uint4 a1 = wa1[(long)ks * 64];
        uint4 b[4];
#pragma unroll
        for (int s = 0; s < 4; ++s) b[s] = xrow[s][ks * 4 + lrow];
        short8 A0 = __builtin_bit_cast(short8, a0);
        short8 A1 = __builtin_bit_cast(short8, a1);
#pragma unroll
        for (int s = 0; s < 4; ++s) {
            short8 B = __builtin_bit_cast(short8, b[s]);
            acc[0][s] = __builtin_amdgcn_mfma_f32_16x16x32_bf16(A0, B, acc[0][s], 0, 0, 0);
            acc[1][s] = __builtin_amdgcn_mfma_f32_16x16x32_bf16(A1, B, acc[1][s], 0, 0, 0);
        }
    }

#pragma unroll
    for (int m = 0; m < 2; ++m) {
        const int obase = (ot0 + m) * 16 + lrow * 4;
        const float b0 = bias[obase], b1 = bias[obase + 1];
        const float b2 = bias[obase + 2], b3 = bias[obase + 3];
#pragma unroll
        for (int s = 0; s < 4; ++s) {
            const int pcol = pw + s * 16 + lcol;
            f32x4 a = acc[m][s];
            float v0 = a[0] + b0, v1 = a[1] + b1, v2 = a[2] + b2, v3 = a[3] + b3;
            if (OUT == 3) {
                v0 = gelu_f(v0); v1 = gelu_f(v1); v2 = gelu_f(v2); v3 = gelu_f(v3);
                uint2 st;
                st.x = bf16_rn(v0) | (bf16_rn(v1) << 16);
                st.y = bf16_rn(v2) | (bf16_rn(v3) << 16);
                *(uint2*)((unsigned*)outp + ((long)n * AREA + pcol) * 288 + (obase >> 1)) = st;
            } else {
                // residual from bf16 o_t (site-major, 144 u32/site)
                uint2 rr = *(const uint2*)(res_u + ((long)n * AREA + pcol) * 144 + (obase >> 1));
                float* fb = (float*)outp;
                float vals[4] = {v0 + bflo(rr.x), v1 + bfhi(rr.x),
                                 v2 + bflo(rr.y), v3 + bfhi(rr.y)};
#pragma unroll
                for (int r = 0; r < 4; ++r) {
                    long addr = ((long)n * 288 + obase + r) * AREA + pcol;
                    fb[addr] = vals[r];
                }
            }
        }
    }
}

// ---------------- deformable attention (R8 fused version) ----------------
// 4 lanes/site: bit0 = role (K/V), bit1 = clip partition; XCD swizzle.
// Writes ONLY bf16 o_t (residual + FFN1 input both read from it).
__global__ __launch_bounds__(256) void deform_attn_kernel(
    const unsigned* __restrict__ qp, const unsigned* __restrict__ kv,
    const float* __restrict__ offs, unsigned* __restrict__ ot)
{
    const int bid = blockIdx.x;
    const int swz = (bid & 7) * 192 + (bid >> 3);    // 1536 = 8 * 192, bijective
    const int t = swz * 256 + threadIdx.x;
    const int role = t & 1;
    const int clip = (t >> 1) & 1;
    const int site = t >> 2;                 // (b*12 + g)*A + a
    const int a = site & (AREA - 1);
    const int g = (site >> 12) % 12;
    const int b = site / (12 * AREA);
    const int py = a >> 6, px = a & 63;
    const float scale = 0.20412414523193150818f;   // 1/sqrt(24)

    float qv[24];
    {
        const uint4* qb = (const uint4*)(qp + ((long)b * AREA + a) * 144 + g * 12);
        uint4 q0 = qb[0], q1 = qb[1], q2 = qb[2];
        unsigned uq[12] = {q0.x, q0.y, q0.z, q0.w, q1.x, q1.y, q1.z, q1.w,
                           q2.x, q2.y, q2.z, q2.w};
#pragma unroll
        for (int j = 0; j < 12; ++j) {
            qv[2 * j]     = bflo(uq[j]) * scale;
            qv[2 * j + 1] = bfhi(uq[j]) * scale;
        }
    }

    float m = -1e30f, l = 0.f;
    float outv[24];
#pragma unroll
    for (int d = 0; d < 24; ++d) outv[d] = 0.f;

    const unsigned* __restrict__ cb =
        kv + (long)((b * 2 + clip) * 12 + g) * AREA * 24 + role * 12;
    const float* __restrict__ obase =
        offs + ((long)b * 432 + (clip * 12 + g) * 18) * AREA;
#pragma unroll 3
    for (int k = 0; k < 9; ++k) {
        float oy = obase[(long)(2 * k) * AREA + a];
        float ox = obase[(long)(2 * k + 1) * AREA + a];
        int ky = k / 3, kx = k - ky * 3;
        float ys = (float)(py + ky - 1) + oy;
        float xs_ = (float)(px + kx - 1) + ox;
        float y0f = floorf(ys), x0f = floorf(xs_);
        float dy = ys - y0f, dx = xs_ - x0f;
        float wy[2] = {1.f - dy, dy};
        float wx[2] = {1.f - dx, dx};
        long  idx4[4];
        float w4[4];
#pragma unroll
        for (int cy = 0; cy < 2; ++cy) {
            float yc = y0f + (float)cy;
            bool vy = (yc >= 0.f) && (yc <= 63.f);
            int yi = (int)fminf(fmaxf(yc, 0.f), 63.f);
#pragma unroll
            for (int cx = 0; cx < 2; ++cx) {
                float xc = x0f + (float)cx;
                bool vx = (xc >= 0.f) && (xc <= 63.f);
                int xi = (int)fminf(fmaxf(xc, 0.f), 63.f);
                w4[cy * 2 + cx] = wy[cy] * wx[cx] * ((vy && vx) ? 1.f : 0.f);
                idx4[cy * 2 + cx] = (long)(yi * 64 + xi) * 24;
            }
        }
        float xs[24];
#pragma unroll
        for (int j = 0; j < 24; ++j) xs[j] = 0.f;
        float sh = 0.f;
#pragma unroll
        for (int c = 0; c < 4; ++c) {
            const uint4* pc = (const uint4*)(cb + idx4[c]);
            uint4 u0 = pc[0], u1 = pc[1], u2 = pc[2];
            unsigned uu[12] = {u0.x, u0.y, u0.z, u0.w,
                               u1.x, u1.y, u1.z, u1.w,
                               u2.x, u2.y, u2.z, u2.w};
            float w = w4[c];
            float d = 0.f;
#pragma unroll
            for (int j = 0; j < 12; ++j) {
                float lo = bflo(uu[j]), hi = bfhi(uu[j]);
                d = fmaf(qv[2 * j], lo, d);
                d = fmaf(qv[2 * j + 1], hi, d);
                xs[2 * j]     = fmaf(w, lo, xs[2 * j]);
                xs[2 * j + 1] = fmaf(w, hi, xs[2 * j + 1]);
            }
            sh = fmaf(w, d, sh);
        }
        float sx = __shfl_xor(sh, 1);
        float s = role ? sx : sh;          // K-lane's full dot
        float mn = fmaxf(m, s);
        float corr = __expf(m - mn);
        float p = __expf(s - mn);
        l = l * corr + p;
        m = mn;
#pragma unroll
        for (int j = 0; j < 24; ++j)
            outv[j] = fmaf(outv[j], corr, p * xs[j]);
    }

    // ---- merge the two clip partitions (lanes differing in bit 1) ----
    float mo  = __shfl_xor(m, 2);
    float lo2 = __shfl_xor(l, 2);
    float mn = fmaxf(m, mo);
    float fs = __expf(m - mn), fo = __expf(mo - mn);
    float lm = l * fs + lo2 * fo;
    float inv = 1.f / lm;
#pragma unroll
    for (int d = 0; d < 24; ++d) {
        float ovo = __shfl_xor(outv[d], 2);
        outv[d] = (outv[d] * fs + ovo * fo) * inv;
    }

    if (role == 1 && clip == 0) {
        unsigned* tb = ot + ((long)b * AREA + a) * 144 + g * 12;
        uint4 s0, s1, s2;
        s0.x = bf16_rn(outv[0])  | (bf16_rn(outv[1])  << 16);
        s0.y = bf16_rn(outv[2])  | (bf16_rn(outv[3])  << 16);
        s0.z = bf16_rn(outv[4])  | (bf16_rn(outv[5])  << 16);
        s0.w = bf16_rn(outv[6])  | (bf16_rn(outv[7])  << 16);
        s1.x = bf16_rn(outv[8])  | (bf16_rn(outv[9])  << 16);
        s1.y = bf16_rn(outv[10]) | (bf16_rn(outv[11]) << 16);
        s1.z = bf16_rn(outv[12]) | (bf16_rn(outv[13]) << 16);
        s1.w = bf16_rn(outv[14]) | (bf16_rn(outv[15]) << 16);
        s2.x = bf16_rn(outv[16]) | (bf16_rn(outv[17]) << 16);
        s2.y = bf16_rn(outv[18]) | (bf16_rn(outv[19]) << 16);
        s2.z = bf16_rn(outv[20]) | (bf16_rn(outv[21]) << 16);
        s2.w = bf16_rn(outv[22]) | (bf16_rn(outv[23]) << 16);
        ((uint4*)tb)[0] = s0; ((uint4*)tb)[1] = s1; ((uint4*)tb)[2] = s2;
    }
}

extern "C" void kernel_launch(void* const* d_in, const int* in_sizes, int n_in,
                              void* d_out, int out_size, void* d_ws, size_t ws_size,
                              hipStream_t stream) {
    const float* q      = (const float*)d_in[0];
    const float* k      = (const float*)d_in[1];
    const float* v      = (const float*)d_in[2];
    const float* offset = (const float*)d_in[3];
    const float* Wq     = (const float*)d_in[4];
    const float* bq     = (const float*)d_in[5];
    const float* Wk     = (const float*)d_in[6];
    const float* bk     = (const float*)d_in[7];
    const float* Wv     = (const float*)d_in[8];
    const float* bv     = (const float*)d_in[9];
    const float* W1     = (const float*)d_in[10];
    const float* b1     = (const float*)d_in[11];
    const float* W2     = (const float*)d_in[12];
    const float* b2     = (const float*)d_in[13];
    float* out = (float*)d_out;
    float* ws  = (float*)d_ws;

    unsigned* qp_u = (unsigned*)ws;                    // 1,179,648 u32
    unsigned* kv_u = (unsigned*)(ws + 2359296);        // 4,718,592 u32
    unsigned* xq   = (unsigned*)(ws + 7077888);        // 1,179,648 u32
    unsigned* xk   = (unsigned*)(ws + 8257536);        // 2,359,296 u32 (x1 aliases)
    unsigned* xv   = (unsigned*)(ws + 10616832);       // 2,359,296 u32 (o_t aliases)
    uint4*    wp   = (uint4*)(ws + 12976128);
    unsigned* x1   = xk;
    unsigned* o_t  = xv;

    // 1) transpose inputs + pack weights
    prep_kernel<<<dim3(2304, 4), dim3(256), 0, stream>>>(
        q, k, v, Wq, Wk, Wv, W1, W2, xq, xk, xv, wp);
    // 2) fused q/k/v projections
    proj_qkv<<<dim3(16, 9, 10), dim3(256), 0, stream>>>(
        xq, xk, xv, wp, bq, bk, bv, qp_u, kv_u);
    // 3) deformable attention -> o_t (bf16 site-major only)
    deform_attn_kernel<<<dim3(1536), dim3(256), 0, stream>>>(
        qp_u, kv_u, offset, o_t);
    // 4) FFN1: o_t(288) -> x1(576) bf16 site-major, GELU
    proj_mfma<3><<<dim3(16, 18, 2), dim3(256), 0, stream>>>(
        o_t, wp + OFF_1, b1, x1, nullptr, 9, 144);
    // 5) FFN2: x1(576) -> d_out f32 chan-major + bf16 residual from o_t
    proj_mfma<0><<<dim3(16, 9, 2), dim3(256), 0, stream>>>(
        x1, wp + OFF_2, b2, out, o_t, 18, 288);
}

// Round 14
// 124.064 us; speedup vs baseline: 1.3332x; 1.0911x over previous
//
#include <hip/hip_runtime.h>

#define AREA 4096

typedef short short8 __attribute__((ext_vector_type(8)));
typedef float f32x4 __attribute__((ext_vector_type(4)));

__device__ __forceinline__ unsigned bf16_rn(float x) {
    unsigned u = __builtin_bit_cast(unsigned, x);
    u += 0x7fffu + ((u >> 16) & 1u);
    return u >> 16;
}
__device__ __forceinline__ float bflo(unsigned u) { return __builtin_bit_cast(float, u << 16); }
__device__ __forceinline__ float bfhi(unsigned u) { return __builtin_bit_cast(float, u & 0xffff0000u); }
__device__ __forceinline__ float gelu_f(float x) {
    return 0.5f * x * (1.f + erff(x * 0.70710678118654752f));
}

// W-frag tile offsets (in uint4 units)
#define OFF_Q 0
#define OFF_K (162 * 64)
#define OFF_V (324 * 64)
#define OFF_1 (486 * 64)
#define OFF_2 (810 * 64)

// ---- prep: y=0/1/2 transpose q/k/v to pixel-major bf16; y=3 pack weights --
__global__ __launch_bounds__(256) void prep_kernel(
    const float* __restrict__ q, const float* __restrict__ k,
    const float* __restrict__ v,
    const float* __restrict__ Wq, const float* __restrict__ Wk,
    const float* __restrict__ Wv, const float* __restrict__ W1,
    const float* __restrict__ W2,
    unsigned* __restrict__ xq, unsigned* __restrict__ xk,
    unsigned* __restrict__ xv, uint4* __restrict__ wp)
{
    if (blockIdx.y < 3) {
        const float* src; unsigned* dst; int nimg;
        switch (blockIdx.y) {
            case 0: src = q; dst = xq; nimg = 2; break;
            case 1: src = k; dst = xk; nimg = 4; break;
            default:src = v; dst = xv; nimg = 4; break;
        }
        int idx = blockIdx.x * 256 + threadIdx.x;
        if (idx >= nimg * AREA * 36) return;
        int a = idx & (AREA - 1);
        int rest = idx >> 12;
        int oct = rest % 36;
        int n = rest / 36;
        const float* s = src + ((long)n * 288 + oct * 8) * AREA + a;
        uint4 u;
        u.x = bf16_rn(s[0])        | (bf16_rn(s[AREA])     << 16);
        u.y = bf16_rn(s[2 * AREA]) | (bf16_rn(s[3 * AREA]) << 16);
        u.z = bf16_rn(s[4 * AREA]) | (bf16_rn(s[5 * AREA]) << 16);
        u.w = bf16_rn(s[6 * AREA]) | (bf16_rn(s[7 * AREA]) << 16);
        *(uint4*)(dst + ((long)n * AREA + a) * 144 + oct * 4) = u;
    } else {
        int gw = blockIdx.x * 4 + (threadIdx.x >> 6);
        if (gw >= 1134) return;
        int lane = threadIdx.x & 63;
        const float* W; int Cin, KS, local, off;
        if      (gw < 162) { W = Wq; Cin = 288; KS = 9;  local = gw;       off = OFF_Q; }
        else if (gw < 324) { W = Wk; Cin = 288; KS = 9;  local = gw - 162; off = OFF_K; }
        else if (gw < 486) { W = Wv; Cin = 288; KS = 9;  local = gw - 324; off = OFF_V; }
        else if (gw < 810) { W = W1; Cin = 288; KS = 9;  local = gw - 486; off = OFF_1; }
        else               { W = W2; Cin = 576; KS = 18; local = gw - 810; off = OFF_2; }
        int ot = local / KS, ks = local - ot * KS;
        int o = ot * 16 + (lane & 15);
        int c0 = ks * 32 + ((lane >> 4) << 3);
        const float4* wr = (const float4*)(W + (long)o * Cin + c0);
        float4 f0 = wr[0], f1 = wr[1];
        uint4 u;
        u.x = bf16_rn(f0.x) | (bf16_rn(f0.y) << 16);
        u.y = bf16_rn(f0.z) | (bf16_rn(f0.w) << 16);
        u.z = bf16_rn(f1.x) | (bf16_rn(f1.y) << 16);
        u.w = bf16_rn(f1.z) | (bf16_rn(f1.w) << 16);
        wp[(long)off + (long)local * 64 + lane] = u;
    }
}

// ---- fused q/k/v MFMA projection (2 out-tiles/block, R8 geometry) -------
// z 0..1: q -> qp_u (bf16 site-major); z 2..5: k -> kv_u[..,0:12];
// z 6..9: v -> kv_u[..,12:24]
__global__ __launch_bounds__(256) void proj_qkv(
    const unsigned* __restrict__ xq, const unsigned* __restrict__ xk,
    const unsigned* __restrict__ xv, const uint4* __restrict__ wp,
    const float* __restrict__ bq, const float* __restrict__ bk,
    const float* __restrict__ bv, unsigned* __restrict__ qp_u,
    unsigned* __restrict__ kv_u)
{
    const int z = blockIdx.z;
    const unsigned* Xt; const uint4* Wp; const float* bias;
    int outmode, voff, n;
    if (z < 2)      { Xt = xq; Wp = wp + OFF_Q; bias = bq; outmode = 1; voff = 0;  n = z; }
    else if (z < 6) { Xt = xk; Wp = wp + OFF_K; bias = bk; outmode = 2; voff = 0;  n = z - 2; }
    else            { Xt = xv; Wp = wp + OFF_V; bias = bv; outmode = 2; voff = 12; n = z - 6; }

    const int tid = threadIdx.x;
    const int lane = tid & 63;
    const int w = tid >> 6;
    const int ot0 = blockIdx.y * 2;
    const int pw = blockIdx.x * 256 + w * 64;
    const int lcol = lane & 15;
    const int lrow = lane >> 4;

    const uint4* xrow[4];
#pragma unroll
    for (int s = 0; s < 4; ++s)
        xrow[s] = (const uint4*)(Xt + ((long)n * AREA + pw + s * 16 + lcol) * 144);
    const uint4* wa0 = Wp + (long)ot0 * 9 * 64 + lane;
    const uint4* wa1 = Wp + (long)(ot0 + 1) * 9 * 64 + lane;

    f32x4 acc[2][4];
#pragma unroll
    for (int m = 0; m < 2; ++m)
#pragma unroll
        for (int s = 0; s < 4; ++s) acc[m][s] = (f32x4){0.f, 0.f, 0.f, 0.f};

    for (int ks = 0; ks < 9; ++ks) {
        uint4 a0 = wa0[(long)ks * 64];
        uint4 a1 = wa1[(long)ks * 64];
        uint4 b[4];
#pragma unroll
        for (int s = 0; s < 4; ++s) b[s] = xrow[s][ks * 4 + lrow];
        short8 A0 = __builtin_bit_cast(short8, a0);
        short8 A1 = __builtin_bit_cast(short8, a1);
#pragma unroll
        for (int s = 0; s < 4; ++s) {
            short8 B = __builtin_bit_cast(short8, b[s]);
            acc[0][s] = __builtin_amdgcn_mfma_f32_16x16x32_bf16(A0, B, acc[0][s], 0, 0, 0);
            acc[1][s] = __builtin_amdgcn_mfma_f32_16x16x32_bf16(A1, B, acc[1][s], 0, 0, 0);
        }
    }

#pragma unroll
    for (int m = 0; m < 2; ++m) {
        const int obase = (ot0 + m) * 16 + lrow * 4;
        const float b0 = bias[obase], b1 = bias[obase + 1];
        const float b2 = bias[obase + 2], b3 = bias[obase + 3];
#pragma unroll
        for (int s = 0; s < 4; ++s) {
            const int pcol = pw + s * 16 + lcol;
            f32x4 a = acc[m][s];
            float v0 = a[0] + b0, v1 = a[1] + b1, v2 = a[2] + b2, v3 = a[3] + b3;
            uint2 st;
            st.x = bf16_rn(v0) | (bf16_rn(v1) << 16);
            st.y = bf16_rn(v2) | (bf16_rn(v3) << 16);
            if (outmode == 1) {
                *(uint2*)(qp_u + ((long)n * AREA + pcol) * 144 + (obase >> 1)) = st;
            } else {
                int g = obase / 24, d0 = obase % 24;
                *(uint2*)(kv_u + ((long)(n * 12 + g) * AREA + pcol) * 24 + voff + (d0 >> 1)) = st;
            }
        }
    }
}

// ---- FFN MFMA projection: single-wave (64-thread) blocks ----------------
// OUT 0: f32 chan-major + bf16 residual from o_t (FFN2)
// OUT 3: bf16 site-major + GELU (FFN1)
template<int OUT>
__global__ __launch_bounds__(64) void proj_mfma(
    const unsigned* __restrict__ Xt, const uint4* __restrict__ Wp,
    const float* __restrict__ bias, void* __restrict__ outp,
    const unsigned* __restrict__ res_u, int KS, int RSu)
{
    const int lane = threadIdx.x;
    const int n = blockIdx.z;
    const int ot0 = blockIdx.y * 2;
    const int pw = blockIdx.x * 64;
    const int lcol = lane & 15;
    const int lrow = lane >> 4;

    const uint4* xrow[4];
#pragma unroll
    for (int s = 0; s < 4; ++s)
        xrow[s] = (const uint4*)(Xt + ((long)n * AREA + pw + s * 16 + lcol) * RSu);
    const uint4* wa0 = Wp + (long)ot0 * KS * 64 + lane;
    const uint4* wa1 = Wp + (long)(ot0 + 1) * KS * 64 + lane;

    f32x4 acc[2][4];
#pragma unroll
    for (int m = 0; m < 2; ++m)
#pragma unroll
        for (int s = 0; s < 4; ++s) acc[m][s] = (f32x4){0.f, 0.f, 0.f, 0.f};

    for (int ks = 0; ks < KS; ++ks) {
        uint4 a0 = wa0[(long)ks * 64];
        uint4 a1 = wa1[(long)ks * 64];
        uint4 b[4];
#pragma unroll
        for (int s = 0; s < 4; ++s) b[s] = xrow[s][ks * 4 + lrow];
        short8 A0 = __builtin_bit_cast(short8, a0);
        short8 A1 = __builtin_bit_cast(short8, a1);
#pragma unroll
        for (int s = 0; s < 4; ++s) {
            short8 B = __builtin_bit_cast(short8, b[s]);
            acc[0][s] = __builtin_amdgcn_mfma_f32_16x16x32_bf16(A0, B, acc[0][s], 0, 0, 0);
            acc[1][s] = __builtin_amdgcn_mfma_f32_16x16x32_bf16(A1, B, acc[1][s], 0, 0, 0);
        }
    }

#pragma unroll
    for (int m = 0; m < 2; ++m) {
        const int obase = (ot0 + m) * 16 + lrow * 4;
        const float b0 = bias[obase], b1 = bias[obase + 1];
        const float b2 = bias[obase + 2], b3 = bias[obase + 3];
#pragma unroll
        for (int s = 0; s < 4; ++s) {
            const int pcol = pw + s * 16 + lcol;
            f32x4 a = acc[m][s];
            float v0 = a[0] + b0, v1 = a[1] + b1, v2 = a[2] + b2, v3 = a[3] + b3;
            if (OUT == 3) {
                v0 = gelu_f(v0); v1 = gelu_f(v1); v2 = gelu_f(v2); v3 = gelu_f(v3);
                uint2 st;
                st.x = bf16_rn(v0) | (bf16_rn(v1) << 16);
                st.y = bf16_rn(v2) | (bf16_rn(v3) << 16);
                *(uint2*)((unsigned*)outp + ((long)n * AREA + pcol) * 288 + (obase >> 1)) = st;
            } else {
                // residual from bf16 o_t (site-major, 144 u32/site)
                uint2 rr = *(const uint2*)(res_u + ((long)n * AREA + pcol) * 144 + (obase >> 1));
                float* fb = (float*)outp;
                float vals[4] = {v0 + bflo(rr.x), v1 + bfhi(rr.x),
                                 v2 + bflo(rr.y), v3 + bfhi(rr.y)};
#pragma unroll
                for (int r = 0; r < 4; ++r) {
                    long addr = ((long)n * 288 + obase + r) * AREA + pcol;
                    fb[addr] = vals[r];
                }
            }
        }
    }
}

// ---------------- deformable attention (R8 fused version) ----------------
// 4 lanes/site: bit0 = role (K/V), bit1 = clip partition; XCD swizzle.
// Writes ONLY bf16 o_t (residual + FFN1 input both read from it).
__global__ __launch_bounds__(256) void deform_attn_kernel(
    const unsigned* __restrict__ qp, const unsigned* __restrict__ kv,
    const float* __restrict__ offs, unsigned* __restrict__ ot)
{
    const int bid = blockIdx.x;
    const int swz = (bid & 7) * 192 + (bid >> 3);    // 1536 = 8 * 192, bijective
    const int t = swz * 256 + threadIdx.x;
    const int role = t & 1;
    const int clip = (t >> 1) & 1;
    const int site = t >> 2;                 // (b*12 + g)*A + a
    const int a = site & (AREA - 1);
    const int g = (site >> 12) % 12;
    const int b = site / (12 * AREA);
    const int py = a >> 6, px = a & 63;
    const float scale = 0.20412414523193150818f;   // 1/sqrt(24)

    float qv[24];
    {
        const uint4* qb = (const uint4*)(qp + ((long)b * AREA + a) * 144 + g * 12);
        uint4 q0 = qb[0], q1 = qb[1], q2 = qb[2];
        unsigned uq[12] = {q0.x, q0.y, q0.z, q0.w, q1.x, q1.y, q1.z, q1.w,
                           q2.x, q2.y, q2.z, q2.w};
#pragma unroll
        for (int j = 0; j < 12; ++j) {
            qv[2 * j]     = bflo(uq[j]) * scale;
            qv[2 * j + 1] = bfhi(uq[j]) * scale;
        }
    }

    float m = -1e30f, l = 0.f;
    float outv[24];
#pragma unroll
    for (int d = 0; d < 24; ++d) outv[d] = 0.f;

    const unsigned* __restrict__ cb =
        kv + (long)((b * 2 + clip) * 12 + g) * AREA * 24 + role * 12;
    const float* __restrict__ obase =
        offs + ((long)b * 432 + (clip * 12 + g) * 18) * AREA;
#pragma unroll 3
    for (int k = 0; k < 9; ++k) {
        float oy = obase[(long)(2 * k) * AREA + a];
        float ox = obase[(long)(2 * k + 1) * AREA + a];
        int ky = k / 3, kx = k - ky * 3;
        float ys = (float)(py + ky - 1) + oy;
        float xs_ = (float)(px + kx - 1) + ox;
        float y0f = floorf(ys), x0f = floorf(xs_);
        float dy = ys - y0f, dx = xs_ - x0f;
        float wy[2] = {1.f - dy, dy};
        float wx[2] = {1.f - dx, dx};
        long  idx4[4];
        float w4[4];
#pragma unroll
        for (int cy = 0; cy < 2; ++cy) {
            float yc = y0f + (float)cy;
            bool vy = (yc >= 0.f) && (yc <= 63.f);
            int yi = (int)fminf(fmaxf(yc, 0.f), 63.f);
#pragma unroll
            for (int cx = 0; cx < 2; ++cx) {
                float xc = x0f + (float)cx;
                bool vx = (xc >= 0.f) && (xc <= 63.f);
                int xi = (int)fminf(fmaxf(xc, 0.f), 63.f);
                w4[cy * 2 + cx] = wy[cy] * wx[cx] * ((vy && vx) ? 1.f : 0.f);
                idx4[cy * 2 + cx] = (long)(yi * 64 + xi) * 24;
            }
        }
        float xs[24];
#pragma unroll
        for (int j = 0; j < 24; ++j) xs[j] = 0.f;
        float sh = 0.f;
#pragma unroll
        for (int c = 0; c < 4; ++c) {
            const uint4* pc = (const uint4*)(cb + idx4[c]);
            uint4 u0 = pc[0], u1 = pc[1], u2 = pc[2];
            unsigned uu[12] = {u0.x, u0.y, u0.z, u0.w,
                               u1.x, u1.y, u1.z, u1.w,
                               u2.x, u2.y, u2.z, u2.w};
            float w = w4[c];
            float d = 0.f;
#pragma unroll
            for (int j = 0; j < 12; ++j) {
                float lo = bflo(uu[j]), hi = bfhi(uu[j]);
                d = fmaf(qv[2 * j], lo, d);
                d = fmaf(qv[2 * j + 1], hi, d);
                xs[2 * j]     = fmaf(w, lo, xs[2 * j]);
                xs[2 * j + 1] = fmaf(w, hi, xs[2 * j + 1]);
            }
            sh = fmaf(w, d, sh);
        }
        float sx = __shfl_xor(sh, 1);
        float s = role ? sx : sh;          // K-lane's full dot
        float mn = fmaxf(m, s);
        float corr = __expf(m - mn);
        float p = __expf(s - mn);
        l = l * corr + p;
        m = mn;
#pragma unroll
        for (int j = 0; j < 24; ++j)
            outv[j] = fmaf(outv[j], corr, p * xs[j]);
    }

    // ---- merge the two clip partitions (lanes differing in bit 1) ----
    float mo  = __shfl_xor(m, 2);
    float lo2 = __shfl_xor(l, 2);
    float mn = fmaxf(m, mo);
    float fs = __expf(m - mn), fo = __expf(mo - mn);
    float lm = l * fs + lo2 * fo;
    float inv = 1.f / lm;
#pragma unroll
    for (int d = 0; d < 24; ++d) {
        float ovo = __shfl_xor(outv[d], 2);
        outv[d] = (outv[d] * fs + ovo * fo) * inv;
    }

    if (role == 1 && clip == 0) {
        unsigned* tb = ot + ((long)b * AREA + a) * 144 + g * 12;
        uint4 s0, s1, s2;
        s0.x = bf16_rn(outv[0])  | (bf16_rn(outv[1])  << 16);
        s0.y = bf16_rn(outv[2])  | (bf16_rn(outv[3])  << 16);
        s0.z = bf16_rn(outv[4])  | (bf16_rn(outv[5])  << 16);
        s0.w = bf16_rn(outv[6])  | (bf16_rn(outv[7])  << 16);
        s1.x = bf16_rn(outv[8])  | (bf16_rn(outv[9])  << 16);
        s1.y = bf16_rn(outv[10]) | (bf16_rn(outv[11]) << 16);
        s1.z = bf16_rn(outv[12]) | (bf16_rn(outv[13]) << 16);
        s1.w = bf16_rn(outv[14]) | (bf16_rn(outv[15]) << 16);
        s2.x = bf16_rn(outv[16]) | (bf16_rn(outv[17]) << 16);
        s2.y = bf16_rn(outv[18]) | (bf16_rn(outv[19]) << 16);
        s2.z = bf16_rn(outv[20]) | (bf16_rn(outv[21]) << 16);
        s2.w = bf16_rn(outv[22]) | (bf16_rn(outv[23]) << 16);
        ((uint4*)tb)[0] = s0; ((uint4*)tb)[1] = s1; ((uint4*)tb)[2] = s2;
    }
}

extern "C" void kernel_launch(void* const* d_in, const int* in_sizes, int n_in,
                              void* d_out, int out_size, void* d_ws, size_t ws_size,
                              hipStream_t stream) {
    const float* q      = (const float*)d_in[0];
    const float* k      = (const float*)d_in[1];
    const float* v      = (const float*)d_in[2];
    const float* offset = (const float*)d_in[3];
    const float* Wq     = (const float*)d_in[4];
    const float* bq     = (const float*)d_in[5];
    const float* Wk     = (const float*)d_in[6];
    const float* bk     = (const float*)d_in[7];
    const float* Wv     = (const float*)d_in[8];
    const float* bv     = (const float*)d_in[9];
    const float* W1     = (const float*)d_in[10];
    const float* b1     = (const float*)d_in[11];
    const float* W2     = (const float*)d_in[12];
    const float* b2     = (const float*)d_in[13];
    float* out = (float*)d_out;
    float* ws  = (float*)d_ws;

    unsigned* qp_u = (unsigned*)ws;                    // 1,179,648 u32
    unsigned* kv_u = (unsigned*)(ws + 2359296);        // 4,718,592 u32
    unsigned* xq   = (unsigned*)(ws + 7077888);        // 1,179,648 u32
    unsigned* xk   = (unsigned*)(ws + 8257536);        // 2,359,296 u32 (x1 aliases)
    unsigned* xv   = (unsigned*)(ws + 10616832);       // 2,359,296 u32 (o_t aliases)
    uint4*    wp   = (uint4*)(ws + 12976128);
    unsigned* x1   = xk;
    unsigned* o_t  = xv;

    // 1) transpose inputs + pack weights
    prep_kernel<<<dim3(2304, 4), dim3(256), 0, stream>>>(
        q, k, v, Wq, Wk, Wv, W1, W2, xq, xk, xv, wp);
    // 2) fused q/k/v projections
    proj_qkv<<<dim3(16, 9, 10), dim3(256), 0, stream>>>(
        xq, xk, xv, wp, bq, bk, bv, qp_u, kv_u);
    // 3) deformable attention -> o_t (bf16 site-major only)
    deform_attn_kernel<<<dim3(1536), dim3(256), 0, stream>>>(
        qp_u, kv_u, offset, o_t);
    // 4) FFN1: o_t(288) -> x1(576) bf16 site-major, GELU (64-thr blocks)
    proj_mfma<3><<<dim3(64, 18, 2), dim3(64), 0, stream>>>(
        o_t, wp + OFF_1, b1, x1, nullptr, 9, 144);
    // 5) FFN2: x1(576) -> d_out f32 + bf16 residual from o_t (64-thr blocks)
    proj_mfma<0><<<dim3(64, 9, 2), dim3(64), 0, stream>>>(
        x1, wp + OFF_2, b2, out, o_t, 18, 288);
}

// Round 15
// 114.807 us; speedup vs baseline: 1.4407x; 1.0806x over previous
//
#include <hip/hip_runtime.h>

#define AREA 4096

typedef short short8 __attribute__((ext_vector_type(8)));
typedef float f32x4 __attribute__((ext_vector_type(4)));

__device__ __forceinline__ unsigned bf16_rn(float x) {
    unsigned u = __builtin_bit_cast(unsigned, x);
    u += 0x7fffu + ((u >> 16) & 1u);
    return u >> 16;
}
__device__ __forceinline__ float bflo(unsigned u) { return __builtin_bit_cast(float, u << 16); }
__device__ __forceinline__ float bfhi(unsigned u) { return __builtin_bit_cast(float, u & 0xffff0000u); }
__device__ __forceinline__ float gelu_f(float x) {
    return 0.5f * x * (1.f + erff(x * 0.70710678118654752f));
}

// W-frag tile offsets (in uint4 units)
#define OFF_Q 0
#define OFF_K (162 * 64)
#define OFF_V (324 * 64)
#define OFF_1 (486 * 64)
#define OFF_2 (810 * 64)

// ---- prep: y=0 LDS-tiled transpose q/k/v -> frag-major [n][ks][a][16 u32];
//      y=1 pack weights into A-frag tiles
__global__ __launch_bounds__(256) void prep_kernel(
    const float* __restrict__ q, const float* __restrict__ k,
    const float* __restrict__ v,
    const float* __restrict__ Wq, const float* __restrict__ Wk,
    const float* __restrict__ Wv, const float* __restrict__ W1,
    const float* __restrict__ W2,
    unsigned* __restrict__ xq, unsigned* __restrict__ xk,
    unsigned* __restrict__ xv, uint4* __restrict__ wp)
{
    if (blockIdx.y == 0) {
        // transpose: 32 px x 288 ch per block; coalesced reads & writes
        __shared__ unsigned lds[32 * 145];
        const int x = blockIdx.x;            // 1280 = 10 imgs x 128
        const int img = x >> 7;
        const int px0 = (x & 127) * 32;
        const float* src; unsigned* dst; int n;
        if (img < 2)      { src = q; dst = xq; n = img; }
        else if (img < 6) { src = k; dst = xk; n = img - 2; }
        else              { src = v; dst = xv; n = img - 6; }
        const int t = threadIdx.x;
        const int px = t & 31;
        const int ci0 = t >> 5;              // 0..7
        const float* sb = src + (long)n * 288 * AREA + px0 + px;
#pragma unroll
        for (int j = 0; j < 18; ++j) {
            int ci = ci0 + j * 8;            // u32 pair index 0..143
            float a = sb[(long)(2 * ci) * AREA];
            float b = sb[(long)(2 * ci + 1) * AREA];
            lds[px * 145 + ci] = bf16_rn(a) | (bf16_rn(b) << 16);
        }
        __syncthreads();
        const int px2 = t >> 3;              // 0..31
        const int off = (t & 7) * 2;         // 0,2,..,14
#pragma unroll
        for (int ks = 0; ks < 9; ++ks) {
            uint2 v2;
            v2.x = lds[px2 * 145 + ks * 16 + off];
            v2.y = lds[px2 * 145 + ks * 16 + off + 1];
            *(uint2*)(dst + (((long)n * 9 + ks) * AREA + px0 + px2) * 16 + off) = v2;
        }
    } else {
        int gw = blockIdx.x * 4 + (threadIdx.x >> 6);
        if (gw >= 1134) return;
        int lane = threadIdx.x & 63;
        const float* W; int Cin, KS, local, off;
        if      (gw < 162) { W = Wq; Cin = 288; KS = 9;  local = gw;       off = OFF_Q; }
        else if (gw < 324) { W = Wk; Cin = 288; KS = 9;  local = gw - 162; off = OFF_K; }
        else if (gw < 486) { W = Wv; Cin = 288; KS = 9;  local = gw - 324; off = OFF_V; }
        else if (gw < 810) { W = W1; Cin = 288; KS = 9;  local = gw - 486; off = OFF_1; }
        else               { W = W2; Cin = 576; KS = 18; local = gw - 810; off = OFF_2; }
        int ot = local / KS, ks = local - ot * KS;
        int o = ot * 16 + (lane & 15);
        int c0 = ks * 32 + ((lane >> 4) << 3);
        const float4* wr = (const float4*)(W + (long)o * Cin + c0);
        float4 f0 = wr[0], f1 = wr[1];
        uint4 u;
        u.x = bf16_rn(f0.x) | (bf16_rn(f0.y) << 16);
        u.y = bf16_rn(f0.z) | (bf16_rn(f0.w) << 16);
        u.z = bf16_rn(f1.x) | (bf16_rn(f1.y) << 16);
        u.w = bf16_rn(f1.z) | (bf16_rn(f1.w) << 16);
        wp[(long)off + (long)local * 64 + lane] = u;
    }
}

// ---- fused q/k/v MFMA projection (B from frag-major Xt) -----------------
// z 0..1: q -> qp_u (bf16 site-major); z 2..5: k -> kv_u[..,0:12];
// z 6..9: v -> kv_u[..,12:24]
__global__ __launch_bounds__(256) void proj_qkv(
    const unsigned* __restrict__ xq, const unsigned* __restrict__ xk,
    const unsigned* __restrict__ xv, const uint4* __restrict__ wp,
    const float* __restrict__ bq, const float* __restrict__ bk,
    const float* __restrict__ bv, unsigned* __restrict__ qp_u,
    unsigned* __restrict__ kv_u)
{
    const int z = blockIdx.z;
    const unsigned* Xt; const uint4* Wp; const float* bias;
    int outmode, voff, n;
    if (z < 2)      { Xt = xq; Wp = wp + OFF_Q; bias = bq; outmode = 1; voff = 0;  n = z; }
    else if (z < 6) { Xt = xk; Wp = wp + OFF_K; bias = bk; outmode = 2; voff = 0;  n = z - 2; }
    else            { Xt = xv; Wp = wp + OFF_V; bias = bv; outmode = 2; voff = 12; n = z - 6; }

    const int tid = threadIdx.x;
    const int lane = tid & 63;
    const int w = tid >> 6;
    const int ot0 = blockIdx.y * 2;
    const int pw = blockIdx.x * 256 + w * 64;
    const int lcol = lane & 15;
    const int lrow = lane >> 4;

    // frag-major: uint4 index ((n*9+ks)*AREA + site)*4 + lrow
    const uint4* Xb = (const uint4*)Xt + (long)n * 9 * AREA * 4;
    const uint4* wa0 = Wp + (long)ot0 * 9 * 64 + lane;
    const uint4* wa1 = Wp + (long)(ot0 + 1) * 9 * 64 + lane;

    f32x4 acc[2][4];
#pragma unroll
    for (int m = 0; m < 2; ++m)
#pragma unroll
        for (int s = 0; s < 4; ++s) acc[m][s] = (f32x4){0.f, 0.f, 0.f, 0.f};

    for (int ks = 0; ks < 9; ++ks) {
        uint4 a0 = wa0[(long)ks * 64];
        uint4 a1 = wa1[(long)ks * 64];
        const uint4* xk4 = Xb + (long)ks * AREA * 4;
        uint4 b[4];
#pragma unroll
        for (int s = 0; s < 4; ++s)
            b[s] = xk4[(long)(pw + s * 16 + lcol) * 4 + lrow];
        short8 A0 = __builtin_bit_cast(short8, a0);
        short8 A1 = __builtin_bit_cast(short8, a1);
#pragma unroll
        for (int s = 0; s < 4; ++s) {
            short8 B = __builtin_bit_cast(short8, b[s]);
            acc[0][s] = __builtin_amdgcn_mfma_f32_16x16x32_bf16(A0, B, acc[0][s], 0, 0, 0);
            acc[1][s] = __builtin_amdgcn_mfma_f32_16x16x32_bf16(A1, B, acc[1][s], 0, 0, 0);
        }
    }

#pragma unroll
    for (int m = 0; m < 2; ++m) {
        const int obase = (ot0 + m) * 16 + lrow * 4;
        const float b0 = bias[obase], b1 = bias[obase + 1];
        const float b2 = bias[obase + 2], b3 = bias[obase + 3];
#pragma unroll
        for (int s = 0; s < 4; ++s) {
            const int pcol = pw + s * 16 + lcol;
            f32x4 a = acc[m][s];
            float v0 = a[0] + b0, v1 = a[1] + b1, v2 = a[2] + b2, v3 = a[3] + b3;
            uint2 st;
            st.x = bf16_rn(v0) | (bf16_rn(v1) << 16);
            st.y = bf16_rn(v2) | (bf16_rn(v3) << 16);
            if (outmode == 1) {
                *(uint2*)(qp_u + ((long)n * AREA + pcol) * 144 + (obase >> 1)) = st;
            } else {
                int g = obase / 24, d0 = obase % 24;
                *(uint2*)(kv_u + ((long)(n * 12 + g) * AREA + pcol) * 24 + voff + (d0 >> 1)) = st;
            }
        }
    }
}

// ---- FFN MFMA projection: single-wave (64-thread) blocks ----------------
// OUT 0: f32 chan-major + bf16 residual from o_t (FFN2)
// OUT 3: bf16 site-major + GELU (FFN1)
template<int OUT>
__global__ __launch_bounds__(64) void proj_mfma(
    const unsigned* __restrict__ Xt, const uint4* __restrict__ Wp,
    const float* __restrict__ bias, void* __restrict__ outp,
    const unsigned* __restrict__ res_u, int KS, int RSu)
{
    const int lane = threadIdx.x;
    const int n = blockIdx.z;
    const int ot0 = blockIdx.y * 2;
    const int pw = blockIdx.x * 64;
    const int lcol = lane & 15;
    const int lrow = lane >> 4;

    const uint4* xrow[4];
#pragma unroll
    for (int s = 0; s < 4; ++s)
        xrow[s] = (const uint4*)(Xt + ((long)n * AREA + pw + s * 16 + lcol) * RSu);
    const uint4* wa0 = Wp + (long)ot0 * KS * 64 + lane;
    const uint4* wa1 = Wp + (long)(ot0 + 1) * KS * 64 + lane;

    f32x4 acc[2][4];
#pragma unroll
    for (int m = 0; m < 2; ++m)
#pragma unroll
        for (int s = 0; s < 4; ++s) acc[m][s] = (f32x4){0.f, 0.f, 0.f, 0.f};

    for (int ks = 0; ks < KS; ++ks) {
        uint4 a0 = wa0[(long)ks * 64];
        uint4 a1 = wa1[(long)ks * 64];
        uint4 b[4];
#pragma unroll
        for (int s = 0; s < 4; ++s) b[s] = xrow[s][ks * 4 + lrow];
        short8 A0 = __builtin_bit_cast(short8, a0);
        short8 A1 = __builtin_bit_cast(short8, a1);
#pragma unroll
        for (int s = 0; s < 4; ++s) {
            short8 B = __builtin_bit_cast(short8, b[s]);
            acc[0][s] = __builtin_amdgcn_mfma_f32_16x16x32_bf16(A0, B, acc[0][s], 0, 0, 0);
            acc[1][s] = __builtin_amdgcn_mfma_f32_16x16x32_bf16(A1, B, acc[1][s], 0, 0, 0);
        }
    }

#pragma unroll
    for (int m = 0; m < 2; ++m) {
        const int obase = (ot0 + m) * 16 + lrow * 4;
        const float b0 = bias[obase], b1 = bias[obase + 1];
        const float b2 = bias[obase + 2], b3 = bias[obase + 3];
#pragma unroll
        for (int s = 0; s < 4; ++s) {
            const int pcol = pw + s * 16 + lcol;
            f32x4 a = acc[m][s];
            float v0 = a[0] + b0, v1 = a[1] + b1, v2 = a[2] + b2, v3 = a[3] + b3;
            if (OUT == 3) {
                v0 = gelu_f(v0); v1 = gelu_f(v1); v2 = gelu_f(v2); v3 = gelu_f(v3);
                uint2 st;
                st.x = bf16_rn(v0) | (bf16_rn(v1) << 16);
                st.y = bf16_rn(v2) | (bf16_rn(v3) << 16);
                *(uint2*)((unsigned*)outp + ((long)n * AREA + pcol) * 288 + (obase >> 1)) = st;
            } else {
                uint2 rr = *(const uint2*)(res_u + ((long)n * AREA + pcol) * 144 + (obase >> 1));
                float* fb = (float*)outp;
                float vals[4] = {v0 + bflo(rr.x), v1 + bfhi(rr.x),
                                 v2 + bflo(rr.y), v3 + bfhi(rr.y)};
#pragma unroll
                for (int r = 0; r < 4; ++r) {
                    long addr = ((long)n * 288 + obase + r) * AREA + pcol;
                    fb[addr] = vals[r];
                }
            }
        }
    }
}

// ---------------- deformable attention (R8 fused version) ----------------
// 4 lanes/site: bit0 = role (K/V), bit1 = clip partition; XCD swizzle.
// Writes ONLY bf16 o_t (residual + FFN1 input both read from it).
__global__ __launch_bounds__(256) void deform_attn_kernel(
    const unsigned* __restrict__ qp, const unsigned* __restrict__ kv,
    const float* __restrict__ offs, unsigned* __restrict__ ot)
{
    const int bid = blockIdx.x;
    const int swz = (bid & 7) * 192 + (bid >> 3);    // 1536 = 8 * 192, bijective
    const int t = swz * 256 + threadIdx.x;
    const int role = t & 1;
    const int clip = (t >> 1) & 1;
    const int site = t >> 2;                 // (b*12 + g)*A + a
    const int a = site & (AREA - 1);
    const int g = (site >> 12) % 12;
    const int b = site / (12 * AREA);
    const int py = a >> 6, px = a & 63;
    const float scale = 0.20412414523193150818f;   // 1/sqrt(24)

    float qv[24];
    {
        const uint4* qb = (const uint4*)(qp + ((long)b * AREA + a) * 144 + g * 12);
        uint4 q0 = qb[0], q1 = qb[1], q2 = qb[2];
        unsigned uq[12] = {q0.x, q0.y, q0.z, q0.w, q1.x, q1.y, q1.z, q1.w,
                           q2.x, q2.y, q2.z, q2.w};
#pragma unroll
        for (int j = 0; j < 12; ++j) {
            qv[2 * j]     = bflo(uq[j]) * scale;
            qv[2 * j + 1] = bfhi(uq[j]) * scale;
        }
    }

    float m = -1e30f, l = 0.f;
    float outv[24];
#pragma unroll
    for (int d = 0; d < 24; ++d) outv[d] = 0.f;

    const unsigned* __restrict__ cb =
        kv + (long)((b * 2 + clip) * 12 + g) * AREA * 24 + role * 12;
    const float* __restrict__ obase =
        offs + ((long)b * 432 + (clip * 12 + g) * 18) * AREA;
#pragma unroll 3
    for (int k = 0; k < 9; ++k) {
        float oy = obase[(long)(2 * k) * AREA + a];
        float ox = obase[(long)(2 * k + 1) * AREA + a];
        int ky = k / 3, kx = k - ky * 3;
        float ys = (float)(py + ky - 1) + oy;
        float xs_ = (float)(px + kx - 1) + ox;
        float y0f = floorf(ys), x0f = floorf(xs_);
        float dy = ys - y0f, dx = xs_ - x0f;
        float wy[2] = {1.f - dy, dy};
        float wx[2] = {1.f - dx, dx};
        long  idx4[4];
        float w4[4];
#pragma unroll
        for (int cy = 0; cy < 2; ++cy) {
            float yc = y0f + (float)cy;
            bool vy = (yc >= 0.f) && (yc <= 63.f);
            int yi = (int)fminf(fmaxf(yc, 0.f), 63.f);
#pragma unroll
            for (int cx = 0; cx < 2; ++cx) {
                float xc = x0f + (float)cx;
                bool vx = (xc >= 0.f) && (xc <= 63.f);
                int xi = (int)fminf(fmaxf(xc, 0.f), 63.f);
                w4[cy * 2 + cx] = wy[cy] * wx[cx] * ((vy && vx) ? 1.f : 0.f);
                idx4[cy * 2 + cx] = (long)(yi * 64 + xi) * 24;
            }
        }
        float xs[24];
#pragma unroll
        for (int j = 0; j < 24; ++j) xs[j] = 0.f;
        float sh = 0.f;
#pragma unroll
        for (int c = 0; c < 4; ++c) {
            const uint4* pc = (const uint4*)(cb + idx4[c]);
            uint4 u0 = pc[0], u1 = pc[1], u2 = pc[2];
            unsigned uu[12] = {u0.x, u0.y, u0.z, u0.w,
                               u1.x, u1.y, u1.z, u1.w,
                               u2.x, u2.y, u2.z, u2.w};
            float w = w4[c];
            float d = 0.f;
#pragma unroll
            for (int j = 0; j < 12; ++j) {
                float lo = bflo(uu[j]), hi = bfhi(uu[j]);
                d = fmaf(qv[2 * j], lo, d);
                d = fmaf(qv[2 * j + 1], hi, d);
                xs[2 * j]     = fmaf(w, lo, xs[2 * j]);
                xs[2 * j + 1] = fmaf(w, hi, xs[2 * j + 1]);
            }
            sh = fmaf(w, d, sh);
        }
        float sx = __shfl_xor(sh, 1);
        float s = role ? sx : sh;          // K-lane's full dot
        float mn = fmaxf(m, s);
        float corr = __expf(m - mn);
        float p = __expf(s - mn);
        l = l * corr + p;
        m = mn;
#pragma unroll
        for (int j = 0; j < 24; ++j)
            outv[j] = fmaf(outv[j], corr, p * xs[j]);
    }

    // ---- merge the two clip partitions (lanes differing in bit 1) ----
    float mo  = __shfl_xor(m, 2);
    float lo2 = __shfl_xor(l, 2);
    float mn = fmaxf(m, mo);
    float fs = __expf(m - mn), fo = __expf(mo - mn);
    float lm = l * fs + lo2 * fo;
    float inv = 1.f / lm;
#pragma unroll
    for (int d = 0; d < 24; ++d) {
        float ovo = __shfl_xor(outv[d], 2);
        outv[d] = (outv[d] * fs + ovo * fo) * inv;
    }

    if (role == 1 && clip == 0) {
        unsigned* tb = ot + ((long)b * AREA + a) * 144 + g * 12;
        uint4 s0, s1, s2;
        s0.x = bf16_rn(outv[0])  | (bf16_rn(outv[1])  << 16);
        s0.y = bf16_rn(outv[2])  | (bf16_rn(outv[3])  << 16);
        s0.z = bf16_rn(outv[4])  | (bf16_rn(outv[5])  << 16);
        s0.w = bf16_rn(outv[6])  | (bf16_rn(outv[7])  << 16);
        s1.x = bf16_rn(outv[8])  | (bf16_rn(outv[9])  << 16);
        s1.y = bf16_rn(outv[10]) | (bf16_rn(outv[11]) << 16);
        s1.z = bf16_rn(outv[12]) | (bf16_rn(outv[13]) << 16);
        s1.w = bf16_rn(outv[14]) | (bf16_rn(outv[15]) << 16);
        s2.x = bf16_rn(outv[16]) | (bf16_rn(outv[17]) << 16);
        s2.y = bf16_rn(outv[18]) | (bf16_rn(outv[19]) << 16);
        s2.z = bf16_rn(outv[20]) | (bf16_rn(outv[21]) << 16);
        s2.w = bf16_rn(outv[22]) | (bf16_rn(outv[23]) << 16);
        ((uint4*)tb)[0] = s0; ((uint4*)tb)[1] = s1; ((uint4*)tb)[2] = s2;
    }
}

extern "C" void kernel_launch(void* const* d_in, const int* in_sizes, int n_in,
                              void* d_out, int out_size, void* d_ws, size_t ws_size,
                              hipStream_t stream) {
    const float* q      = (const float*)d_in[0];
    const float* k      = (const float*)d_in[1];
    const float* v      = (const float*)d_in[2];
    const float* offset = (const float*)d_in[3];
    const float* Wq     = (const float*)d_in[4];
    const float* bq     = (const float*)d_in[5];
    const float* Wk     = (const float*)d_in[6];
    const float* bk     = (const float*)d_in[7];
    const float* Wv     = (const float*)d_in[8];
    const float* bv     = (const float*)d_in[9];
    const float* W1     = (const float*)d_in[10];
    const float* b1     = (const float*)d_in[11];
    const float* W2     = (const float*)d_in[12];
    const float* b2     = (const float*)d_in[13];
    float* out = (float*)d_out;
    float* ws  = (float*)d_ws;

    unsigned* qp_u = (unsigned*)ws;                    // 1,179,648 u32
    unsigned* kv_u = (unsigned*)(ws + 2359296);        // 4,718,592 u32
    unsigned* xq   = (unsigned*)(ws + 7077888);        // 1,179,648 u32
    unsigned* xk   = (unsigned*)(ws + 8257536);        // 2,359,296 u32 (x1 aliases)
    unsigned* xv   = (unsigned*)(ws + 10616832);       // 2,359,296 u32 (o_t aliases)
    uint4*    wp   = (uint4*)(ws + 12976128);
    unsigned* x1   = xk;
    unsigned* o_t  = xv;

    // 1) LDS-tiled transpose (coalesced) + pack weights
    prep_kernel<<<dim3(1280, 2), dim3(256), 0, stream>>>(
        q, k, v, Wq, Wk, Wv, W1, W2, xq, xk, xv, wp);
    // 2) fused q/k/v projections (frag-major B)
    proj_qkv<<<dim3(16, 9, 10), dim3(256), 0, stream>>>(
        xq, xk, xv, wp, bq, bk, bv, qp_u, kv_u);
    // 3) deformable attention -> o_t (bf16 site-major only)
    deform_attn_kernel<<<dim3(1536), dim3(256), 0, stream>>>(
        qp_u, kv_u, offset, o_t);
    // 4) FFN1: o_t(288) -> x1(576) bf16 site-major, GELU (64-thr blocks)
    proj_mfma<3><<<dim3(64, 18, 2), dim3(64), 0, stream>>>(
        o_t, wp + OFF_1, b1, x1, nullptr, 9, 144);
    // 5) FFN2: x1(576) -> d_out f32 + bf16 residual from o_t (64-thr blocks)
    proj_mfma<0><<<dim3(64, 9, 2), dim3(64), 0, stream>>>(
        x1, wp + OFF_2, b2, out, o_t, 18, 288);
}

// Round 16
// 113.840 us; speedup vs baseline: 1.4529x; 1.0085x over previous
//
#include <hip/hip_runtime.h>

#define AREA 4096

typedef short short8 __attribute__((ext_vector_type(8)));
typedef float f32x4 __attribute__((ext_vector_type(4)));

__device__ __forceinline__ unsigned bf16_rn(float x) {
    unsigned u = __builtin_bit_cast(unsigned, x);
    u += 0x7fffu + ((u >> 16) & 1u);
    return u >> 16;
}
__device__ __forceinline__ float bflo(unsigned u) { return __builtin_bit_cast(float, u << 16); }
__device__ __forceinline__ float bfhi(unsigned u) { return __builtin_bit_cast(float, u & 0xffff0000u); }
__device__ __forceinline__ float gelu_f(float x) {
    return 0.5f * x * (1.f + erff(x * 0.70710678118654752f));
}

// W-frag tile offsets (in uint4 units)
#define OFF_Q 0
#define OFF_K (162 * 64)
#define OFF_V (324 * 64)
#define OFF_1 (486 * 64)
#define OFF_2 (810 * 64)

// ---- prep: y=0 LDS-tiled transpose q/k/v -> frag-major [n][ks][a][16 u32];
//      y=1 pack weights into A-frag tiles
__global__ __launch_bounds__(256) void prep_kernel(
    const float* __restrict__ q, const float* __restrict__ k,
    const float* __restrict__ v,
    const float* __restrict__ Wq, const float* __restrict__ Wk,
    const float* __restrict__ Wv, const float* __restrict__ W1,
    const float* __restrict__ W2,
    unsigned* __restrict__ xq, unsigned* __restrict__ xk,
    unsigned* __restrict__ xv, uint4* __restrict__ wp)
{
    if (blockIdx.y == 0) {
        // transpose: 32 px x 288 ch per block; coalesced reads & writes
        __shared__ unsigned lds[32 * 145];
        const int x = blockIdx.x;            // 1280 = 10 imgs x 128
        const int img = x >> 7;
        const int px0 = (x & 127) * 32;
        const float* src; unsigned* dst; int n;
        if (img < 2)      { src = q; dst = xq; n = img; }
        else if (img < 6) { src = k; dst = xk; n = img - 2; }
        else              { src = v; dst = xv; n = img - 6; }
        const int t = threadIdx.x;
        const int px = t & 31;
        const int ci0 = t >> 5;              // 0..7
        const float* sb = src + (long)n * 288 * AREA + px0 + px;
#pragma unroll
        for (int j = 0; j < 18; ++j) {
            int ci = ci0 + j * 8;            // u32 pair index 0..143
            float a = sb[(long)(2 * ci) * AREA];
            float b = sb[(long)(2 * ci + 1) * AREA];
            lds[px * 145 + ci] = bf16_rn(a) | (bf16_rn(b) << 16);
        }
        __syncthreads();
        const int px2 = t >> 3;              // 0..31
        const int off = (t & 7) * 2;         // 0,2,..,14
#pragma unroll
        for (int ks = 0; ks < 9; ++ks) {
            uint2 v2;
            v2.x = lds[px2 * 145 + ks * 16 + off];
            v2.y = lds[px2 * 145 + ks * 16 + off + 1];
            *(uint2*)(dst + (((long)n * 9 + ks) * AREA + px0 + px2) * 16 + off) = v2;
        }
    } else {
        int gw = blockIdx.x * 4 + (threadIdx.x >> 6);
        if (gw >= 1134) return;
        int lane = threadIdx.x & 63;
        const float* W; int Cin, KS, local, off;
        if      (gw < 162) { W = Wq; Cin = 288; KS = 9;  local = gw;       off = OFF_Q; }
        else if (gw < 324) { W = Wk; Cin = 288; KS = 9;  local = gw - 162; off = OFF_K; }
        else if (gw < 486) { W = Wv; Cin = 288; KS = 9;  local = gw - 324; off = OFF_V; }
        else if (gw < 810) { W = W1; Cin = 288; KS = 9;  local = gw - 486; off = OFF_1; }
        else               { W = W2; Cin = 576; KS = 18; local = gw - 810; off = OFF_2; }
        int ot = local / KS, ks = local - ot * KS;
        int o = ot * 16 + (lane & 15);
        int c0 = ks * 32 + ((lane >> 4) << 3);
        const float4* wr = (const float4*)(W + (long)o * Cin + c0);
        float4 f0 = wr[0], f1 = wr[1];
        uint4 u;
        u.x = bf16_rn(f0.x) | (bf16_rn(f0.y) << 16);
        u.y = bf16_rn(f0.z) | (bf16_rn(f0.w) << 16);
        u.z = bf16_rn(f1.x) | (bf16_rn(f1.y) << 16);
        u.w = bf16_rn(f1.z) | (bf16_rn(f1.w) << 16);
        wp[(long)off + (long)local * 64 + lane] = u;
    }
}

// ---- fused q/k/v MFMA projection: single-wave (64-thread) blocks --------
// z 0..1: q -> qp_u (bf16 site-major); z 2..5: k -> kv_u[..,0:12];
// z 6..9: v -> kv_u[..,12:24]
__global__ __launch_bounds__(64) void proj_qkv(
    const unsigned* __restrict__ xq, const unsigned* __restrict__ xk,
    const unsigned* __restrict__ xv, const uint4* __restrict__ wp,
    const float* __restrict__ bq, const float* __restrict__ bk,
    const float* __restrict__ bv, unsigned* __restrict__ qp_u,
    unsigned* __restrict__ kv_u)
{
    const int z = blockIdx.z;
    const unsigned* Xt; const uint4* Wp; const float* bias;
    int outmode, voff, n;
    if (z < 2)      { Xt = xq; Wp = wp + OFF_Q; bias = bq; outmode = 1; voff = 0;  n = z; }
    else if (z < 6) { Xt = xk; Wp = wp + OFF_K; bias = bk; outmode = 2; voff = 0;  n = z - 2; }
    else            { Xt = xv; Wp = wp + OFF_V; bias = bv; outmode = 2; voff = 12; n = z - 6; }

    const int lane = threadIdx.x;
    const int ot0 = blockIdx.y * 2;
    const int pw = blockIdx.x * 64;
    const int lcol = lane & 15;
    const int lrow = lane >> 4;

    // frag-major: uint4 index ((n*9+ks)*AREA + site)*4 + lrow
    const uint4* Xb = (const uint4*)Xt + (long)n * 9 * AREA * 4;
    const uint4* wa0 = Wp + (long)ot0 * 9 * 64 + lane;
    const uint4* wa1 = Wp + (long)(ot0 + 1) * 9 * 64 + lane;

    f32x4 acc[2][4];
#pragma unroll
    for (int m = 0; m < 2; ++m)
#pragma unroll
        for (int s = 0; s < 4; ++s) acc[m][s] = (f32x4){0.f, 0.f, 0.f, 0.f};

    for (int ks = 0; ks < 9; ++ks) {
        uint4 a0 = wa0[(long)ks * 64];
        uint4 a1 = wa1[(long)ks * 64];
        const uint4* xk4 = Xb + (long)ks * AREA * 4;
        uint4 b[4];
#pragma unroll
        for (int s = 0; s < 4; ++s)
            b[s] = xk4[(long)(pw + s * 16 + lcol) * 4 + lrow];
        short8 A0 = __builtin_bit_cast(short8, a0);
        short8 A1 = __builtin_bit_cast(short8, a1);
#pragma unroll
        for (int s = 0; s < 4; ++s) {
            short8 B = __builtin_bit_cast(short8, b[s]);
            acc[0][s] = __builtin_amdgcn_mfma_f32_16x16x32_bf16(A0, B, acc[0][s], 0, 0, 0);
            acc[1][s] = __builtin_amdgcn_mfma_f32_16x16x32_bf16(A1, B, acc[1][s], 0, 0, 0);
        }
    }

#pragma unroll
    for (int m = 0; m < 2; ++m) {
        const int obase = (ot0 + m) * 16 + lrow * 4;
        const float b0 = bias[obase], b1 = bias[obase + 1];
        const float b2 = bias[obase + 2], b3 = bias[obase + 3];
#pragma unroll
        for (int s = 0; s < 4; ++s) {
            const int pcol = pw + s * 16 + lcol;
            f32x4 a = acc[m][s];
            float v0 = a[0] + b0, v1 = a[1] + b1, v2 = a[2] + b2, v3 = a[3] + b3;
            uint2 st;
            st.x = bf16_rn(v0) | (bf16_rn(v1) << 16);
            st.y = bf16_rn(v2) | (bf16_rn(v3) << 16);
            if (outmode == 1) {
                *(uint2*)(qp_u + ((long)n * AREA + pcol) * 144 + (obase >> 1)) = st;
            } else {
                int g = obase / 24, d0 = obase % 24;
                *(uint2*)(kv_u + ((long)(n * 12 + g) * AREA + pcol) * 24 + voff + (d0 >> 1)) = st;
            }
        }
    }
}

// ---- FFN MFMA projection: single-wave (64-thread) blocks ----------------
// OUT 0: f32 chan-major + bf16 residual from o_t (FFN2)
// OUT 3: bf16 site-major + GELU (FFN1)
template<int OUT>
__global__ __launch_bounds__(64) void proj_mfma(
    const unsigned* __restrict__ Xt, const uint4* __restrict__ Wp,
    const float* __restrict__ bias, void* __restrict__ outp,
    const unsigned* __restrict__ res_u, int KS, int RSu)
{
    const int lane = threadIdx.x;
    const int n = blockIdx.z;
    const int ot0 = blockIdx.y * 2;
    const int pw = blockIdx.x * 64;
    const int lcol = lane & 15;
    const int lrow = lane >> 4;

    const uint4* xrow[4];
#pragma unroll
    for (int s = 0; s < 4; ++s)
        xrow[s] = (const uint4*)(Xt + ((long)n * AREA + pw + s * 16 + lcol) * RSu);
    const uint4* wa0 = Wp + (long)ot0 * KS * 64 + lane;
    const uint4* wa1 = Wp + (long)(ot0 + 1) * KS * 64 + lane;

    f32x4 acc[2][4];
#pragma unroll
    for (int m = 0; m < 2; ++m)
#pragma unroll
        for (int s = 0; s < 4; ++s) acc[m][s] = (f32x4){0.f, 0.f, 0.f, 0.f};

    for (int ks = 0; ks < KS; ++ks) {
        uint4 a0 = wa0[(long)ks * 64];
        uint4 a1 = wa1[(long)ks * 64];
        uint4 b[4];
#pragma unroll
        for (int s = 0; s < 4; ++s) b[s] = xrow[s][ks * 4 + lrow];
        short8 A0 = __builtin_bit_cast(short8, a0);
        short8 A1 = __builtin_bit_cast(short8, a1);
#pragma unroll
        for (int s = 0; s < 4; ++s) {
            short8 B = __builtin_bit_cast(short8, b[s]);
            acc[0][s] = __builtin_amdgcn_mfma_f32_16x16x32_bf16(A0, B, acc[0][s], 0, 0, 0);
            acc[1][s] = __builtin_amdgcn_mfma_f32_16x16x32_bf16(A1, B, acc[1][s], 0, 0, 0);
        }
    }

#pragma unroll
    for (int m = 0; m < 2; ++m) {
        const int obase = (ot0 + m) * 16 + lrow * 4;
        const float b0 = bias[obase], b1 = bias[obase + 1];
        const float b2 = bias[obase + 2], b3 = bias[obase + 3];
#pragma unroll
        for (int s = 0; s < 4; ++s) {
            const int pcol = pw + s * 16 + lcol;
            f32x4 a = acc[m][s];
            float v0 = a[0] + b0, v1 = a[1] + b1, v2 = a[2] + b2, v3 = a[3] + b3;
            if (OUT == 3) {
                v0 = gelu_f(v0); v1 = gelu_f(v1); v2 = gelu_f(v2); v3 = gelu_f(v3);
                uint2 st;
                st.x = bf16_rn(v0) | (bf16_rn(v1) << 16);
                st.y = bf16_rn(v2) | (bf16_rn(v3) << 16);
                *(uint2*)((unsigned*)outp + ((long)n * AREA + pcol) * 288 + (obase >> 1)) = st;
            } else {
                uint2 rr = *(const uint2*)(res_u + ((long)n * AREA + pcol) * 144 + (obase >> 1));
                float* fb = (float*)outp;
                float vals[4] = {v0 + bflo(rr.x), v1 + bfhi(rr.x),
                                 v2 + bflo(rr.y), v3 + bfhi(rr.y)};
#pragma unroll
                for (int r = 0; r < 4; ++r) {
                    long addr = ((long)n * 288 + obase + r) * AREA + pcol;
                    fb[addr] = vals[r];
                }
            }
        }
    }
}

// ---------------- deformable attention (R8 fused version) ----------------
// 4 lanes/site: bit0 = role (K/V), bit1 = clip partition; XCD swizzle.
// Writes ONLY bf16 o_t (residual + FFN1 input both read from it).
__global__ __launch_bounds__(256) void deform_attn_kernel(
    const unsigned* __restrict__ qp, const unsigned* __restrict__ kv,
    const float* __restrict__ offs, unsigned* __restrict__ ot)
{
    const int bid = blockIdx.x;
    const int swz = (bid & 7) * 192 + (bid >> 3);    // 1536 = 8 * 192, bijective
    const int t = swz * 256 + threadIdx.x;
    const int role = t & 1;
    const int clip = (t >> 1) & 1;
    const int site = t >> 2;                 // (b*12 + g)*A + a
    const int a = site & (AREA - 1);
    const int g = (site >> 12) % 12;
    const int b = site / (12 * AREA);
    const int py = a >> 6, px = a & 63;
    const float scale = 0.20412414523193150818f;   // 1/sqrt(24)

    float qv[24];
    {
        const uint4* qb = (const uint4*)(qp + ((long)b * AREA + a) * 144 + g * 12);
        uint4 q0 = qb[0], q1 = qb[1], q2 = qb[2];
        unsigned uq[12] = {q0.x, q0.y, q0.z, q0.w, q1.x, q1.y, q1.z, q1.w,
                           q2.x, q2.y, q2.z, q2.w};
#pragma unroll
        for (int j = 0; j < 12; ++j) {
            qv[2 * j]     = bflo(uq[j]) * scale;
            qv[2 * j + 1] = bfhi(uq[j]) * scale;
        }
    }

    float m = -1e30f, l = 0.f;
    float outv[24];
#pragma unroll
    for (int d = 0; d < 24; ++d) outv[d] = 0.f;

    const unsigned* __restrict__ cb =
        kv + (long)((b * 2 + clip) * 12 + g) * AREA * 24 + role * 12;
    const float* __restrict__ obase =
        offs + ((long)b * 432 + (clip * 12 + g) * 18) * AREA;
#pragma unroll 3
    for (int k = 0; k < 9; ++k) {
        float oy = obase[(long)(2 * k) * AREA + a];
        float ox = obase[(long)(2 * k + 1) * AREA + a];
        int ky = k / 3, kx = k - ky * 3;
        float ys = (float)(py + ky - 1) + oy;
        float xs_ = (float)(px + kx - 1) + ox;
        float y0f = floorf(ys), x0f = floorf(xs_);
        float dy = ys - y0f, dx = xs_ - x0f;
        float wy[2] = {1.f - dy, dy};
        float wx[2] = {1.f - dx, dx};
        long  idx4[4];
        float w4[4];
#pragma unroll
        for (int cy = 0; cy < 2; ++cy) {
            float yc = y0f + (float)cy;
            bool vy = (yc >= 0.f) && (yc <= 63.f);
            int yi = (int)fminf(fmaxf(yc, 0.f), 63.f);
#pragma unroll
            for (int cx = 0; cx < 2; ++cx) {
                float xc = x0f + (float)cx;
                bool vx = (xc >= 0.f) && (xc <= 63.f);
                int xi = (int)fminf(fmaxf(xc, 0.f), 63.f);
                w4[cy * 2 + cx] = wy[cy] * wx[cx] * ((vy && vx) ? 1.f : 0.f);
                idx4[cy * 2 + cx] = (long)(yi * 64 + xi) * 24;
            }
        }
        float xs[24];
#pragma unroll
        for (int j = 0; j < 24; ++j) xs[j] = 0.f;
        float sh = 0.f;
#pragma unroll
        for (int c = 0; c < 4; ++c) {
            const uint4* pc = (const uint4*)(cb + idx4[c]);
            uint4 u0 = pc[0], u1 = pc[1], u2 = pc[2];
            unsigned uu[12] = {u0.x, u0.y, u0.z, u0.w,
                               u1.x, u1.y, u1.z, u1.w,
                               u2.x, u2.y, u2.z, u2.w};
            float w = w4[c];
            float d = 0.f;
#pragma unroll
            for (int j = 0; j < 12; ++j) {
                float lo = bflo(uu[j]), hi = bfhi(uu[j]);
                d = fmaf(qv[2 * j], lo, d);
                d = fmaf(qv[2 * j + 1], hi, d);
                xs[2 * j]     = fmaf(w, lo, xs[2 * j]);
                xs[2 * j + 1] = fmaf(w, hi, xs[2 * j + 1]);
            }
            sh = fmaf(w, d, sh);
        }
        float sx = __shfl_xor(sh, 1);
        float s = role ? sx : sh;          // K-lane's full dot
        float mn = fmaxf(m, s);
        float corr = __expf(m - mn);
        float p = __expf(s - mn);
        l = l * corr + p;
        m = mn;
#pragma unroll
        for (int j = 0; j < 24; ++j)
            outv[j] = fmaf(outv[j], corr, p * xs[j]);
    }

    // ---- merge the two clip partitions (lanes differing in bit 1) ----
    float mo  = __shfl_xor(m, 2);
    float lo2 = __shfl_xor(l, 2);
    float mn = fmaxf(m, mo);
    float fs = __expf(m - mn), fo = __expf(mo - mn);
    float lm = l * fs + lo2 * fo;
    float inv = 1.f / lm;
#pragma unroll
    for (int d = 0; d < 24; ++d) {
        float ovo = __shfl_xor(outv[d], 2);
        outv[d] = (outv[d] * fs + ovo * fo) * inv;
    }

    if (role == 1 && clip == 0) {
        unsigned* tb = ot + ((long)b * AREA + a) * 144 + g * 12;
        uint4 s0, s1, s2;
        s0.x = bf16_rn(outv[0])  | (bf16_rn(outv[1])  << 16);
        s0.y = bf16_rn(outv[2])  | (bf16_rn(outv[3])  << 16);
        s0.z = bf16_rn(outv[4])  | (bf16_rn(outv[5])  << 16);
        s0.w = bf16_rn(outv[6])  | (bf16_rn(outv[7])  << 16);
        s1.x = bf16_rn(outv[8])  | (bf16_rn(outv[9])  << 16);
        s1.y = bf16_rn(outv[10]) | (bf16_rn(outv[11]) << 16);
        s1.z = bf16_rn(outv[12]) | (bf16_rn(outv[13]) << 16);
        s1.w = bf16_rn(outv[14]) | (bf16_rn(outv[15]) << 16);
        s2.x = bf16_rn(outv[16]) | (bf16_rn(outv[17]) << 16);
        s2.y = bf16_rn(outv[18]) | (bf16_rn(outv[19]) << 16);
        s2.z = bf16_rn(outv[20]) | (bf16_rn(outv[21]) << 16);
        s2.w = bf16_rn(outv[22]) | (bf16_rn(outv[23]) << 16);
        ((uint4*)tb)[0] = s0; ((uint4*)tb)[1] = s1; ((uint4*)tb)[2] = s2;
    }
}

extern "C" void kernel_launch(void* const* d_in, const int* in_sizes, int n_in,
                              void* d_out, int out_size, void* d_ws, size_t ws_size,
                              hipStream_t stream) {
    const float* q      = (const float*)d_in[0];
    const float* k      = (const float*)d_in[1];
    const float* v      = (const float*)d_in[2];
    const float* offset = (const float*)d_in[3];
    const float* Wq     = (const float*)d_in[4];
    const float* bq     = (const float*)d_in[5];
    const float* Wk     = (const float*)d_in[6];
    const float* bk     = (const float*)d_in[7];
    const float* Wv     = (const float*)d_in[8];
    const float* bv     = (const float*)d_in[9];
    const float* W1     = (const float*)d_in[10];
    const float* b1     = (const float*)d_in[11];
    const float* W2     = (const float*)d_in[12];
    const float* b2     = (const float*)d_in[13];
    float* out = (float*)d_out;
    float* ws  = (float*)d_ws;

    unsigned* qp_u = (unsigned*)ws;                    // 1,179,648 u32
    unsigned* kv_u = (unsigned*)(ws + 2359296);        // 4,718,592 u32
    unsigned* xq   = (unsigned*)(ws + 7077888);        // 1,179,648 u32
    unsigned* xk   = (unsigned*)(ws + 8257536);        // 2,359,296 u32 (x1 aliases)
    unsigned* xv   = (unsigned*)(ws + 10616832);       // 2,359,296 u32 (o_t aliases)
    uint4*    wp   = (uint4*)(ws + 12976128);
    unsigned* x1   = xk;
    unsigned* o_t  = xv;

    // 1) LDS-tiled transpose (coalesced) + pack weights
    prep_kernel<<<dim3(1280, 2), dim3(256), 0, stream>>>(
        q, k, v, Wq, Wk, Wv, W1, W2, xq, xk, xv, wp);
    // 2) fused q/k/v projections (frag-major B, 64-thr blocks)
    proj_qkv<<<dim3(64, 9, 10), dim3(64), 0, stream>>>(
        xq, xk, xv, wp, bq, bk, bv, qp_u, kv_u);
    // 3) deformable attention -> o_t (bf16 site-major only)
    deform_attn_kernel<<<dim3(1536), dim3(256), 0, stream>>>(
        qp_u, kv_u, offset, o_t);
    // 4) FFN1: o_t(288) -> x1(576) bf16 site-major, GELU (64-thr blocks)
    proj_mfma<3><<<dim3(64, 18, 2), dim3(64), 0, stream>>>(
        o_t, wp + OFF_1, b1, x1, nullptr, 9, 144);
    // 5) FFN2: x1(576) -> d_out f32 + bf16 residual from o_t (64-thr blocks)
    proj_mfma<0><<<dim3(64, 9, 2), dim3(64), 0, stream>>>(
        x1, wp + OFF_2, b2, out, o_t, 18, 288);
}